// Round 4
// baseline (5478.267 us; speedup 1.0000x reference)
//
#include <hip/hip_runtime.h>

typedef unsigned long long u64;
typedef unsigned int u32;

#define W1H 1023   // after conv1+pool
#define W2H 1021   // after conv2
#define W3H 1019   // after conv3
#define NPIX (W3H * W3H)          // 1,038,361 < 2^20
#define IDXMASK 0xFFFFFull

// ---------------- conv1 (3->10, 3x3) + bias + prelu + maxpool2, f64 ----------------
__global__ __launch_bounds__(256) void k_conv1(
    const float* __restrict__ x, const float* __restrict__ w1,
    const float* __restrict__ b1, const float* __restrict__ p1,
    double* __restrict__ P)
{
    __shared__ double sw[270];
    __shared__ double sb[10], sp[10];
    int t = threadIdx.y * 64 + threadIdx.x;
    for (int i = t; i < 270; i += 256) sw[i] = (double)w1[i];
    if (t < 10) { sb[t] = (double)b1[t]; sp[t] = (double)p1[t]; }
    __syncthreads();
    int px = blockIdx.x * 64 + threadIdx.x;
    int py = blockIdx.y * 4 + threadIdx.y;
    if (px >= W1H || py >= W1H) return;
    int ix = px * 2, iy = py * 2;
    double acc[10][4];
    #pragma unroll
    for (int ch = 0; ch < 10; ++ch) {
        acc[ch][0] = 0.0; acc[ch][1] = 0.0; acc[ch][2] = 0.0; acc[ch][3] = 0.0;
    }
    for (int c = 0; c < 3; ++c) {
        double in[4][4];
        #pragma unroll
        for (int u = 0; u < 4; ++u) {
            const float* row = x + ((size_t)c * 2048 + (iy + u)) * 2048 + ix;
            in[u][0] = (double)row[0]; in[u][1] = (double)row[1];
            in[u][2] = (double)row[2]; in[u][3] = (double)row[3];
        }
        #pragma unroll
        for (int ch = 0; ch < 10; ++ch) {
            const double* wp = sw + (ch * 3 + c) * 9;
            #pragma unroll
            for (int u = 0; u < 3; ++u)
                #pragma unroll
                for (int v = 0; v < 3; ++v) {
                    double w = wp[u * 3 + v];
                    acc[ch][0] = fma(in[u][v],         w, acc[ch][0]);
                    acc[ch][1] = fma(in[u][v + 1],     w, acc[ch][1]);
                    acc[ch][2] = fma(in[u + 1][v],     w, acc[ch][2]);
                    acc[ch][3] = fma(in[u + 1][v + 1], w, acc[ch][3]);
                }
        }
    }
    #pragma unroll
    for (int ch = 0; ch < 10; ++ch) {
        double m = fmax(fmax(acc[ch][0], acc[ch][1]), fmax(acc[ch][2], acc[ch][3])) + sb[ch];
        double r = m >= 0.0 ? m : sp[ch] * m;
        P[((size_t)ch * W1H + py) * W1H + px] = r;
    }
}

// ---------------- conv2 (10->16, 3x3) + bias + prelu, f64, 2px/thread ----------------
__global__ __launch_bounds__(256) void k_conv2(
    const double* __restrict__ P, const float* __restrict__ w2,
    const float* __restrict__ b2, const float* __restrict__ p2,
    double* __restrict__ H2)
{
    __shared__ double sw[1440];   // [c][o][9]
    __shared__ double sb[16], sp[16];
    int t = threadIdx.y * 64 + threadIdx.x;
    for (int i = t; i < 1440; i += 256) {
        int o = i / 90, r = i % 90, c = r / 9, k = r % 9;
        sw[(c * 16 + o) * 9 + k] = (double)w2[i];
    }
    if (t < 16) { sb[t] = (double)b2[t]; sp[t] = (double)p2[t]; }
    __syncthreads();
    int px0 = blockIdx.x * 128 + threadIdx.x;
    int px1 = px0 + 64;
    int py = blockIdx.y * 4 + threadIdx.y;
    if (px0 >= W2H || py >= W2H) return;
    bool has1 = (px1 < W2H);
    double acc0[16], acc1[16];
    #pragma unroll
    for (int o = 0; o < 16; ++o) { acc0[o] = 0.0; acc1[o] = 0.0; }
    for (int c = 0; c < 10; ++c) {
        double in0[9], in1[9];
        #pragma unroll
        for (int u = 0; u < 3; ++u) {
            const double* row = P + ((size_t)c * W1H + py + u) * W1H + px0;
            in0[u * 3] = row[0]; in0[u * 3 + 1] = row[1]; in0[u * 3 + 2] = row[2];
            if (has1) { in1[u * 3] = row[64]; in1[u * 3 + 1] = row[65]; in1[u * 3 + 2] = row[66]; }
        }
        const double* wc = sw + c * 144;
        #pragma unroll
        for (int o = 0; o < 16; ++o) {
            const double* wp = wc + o * 9;
            double s = acc0[o];
            #pragma unroll
            for (int k = 0; k < 9; ++k) s = fma(in0[k], wp[k], s);
            acc0[o] = s;
            if (has1) {
                double q = acc1[o];
                #pragma unroll
                for (int k = 0; k < 9; ++k) q = fma(in1[k], wp[k], q);
                acc1[o] = q;
            }
        }
    }
    #pragma unroll
    for (int o = 0; o < 16; ++o) {
        double v = acc0[o] + sb[o];
        v = v >= 0.0 ? v : sp[o] * v;
        H2[((size_t)o * W2H + py) * W2H + px0] = v;
        if (has1) {
            double w = acc1[o] + sb[o];
            w = w >= 0.0 ? w : sp[o] * w;
            H2[((size_t)o * W2H + py) * W2H + px1] = w;
        }
    }
}

// ------- conv3 (16->32) + prelu + cls head + softmax + candidate push, f64, 2px -------
__global__ __launch_bounds__(256) void k_conv3(
    const double* __restrict__ H2, const float* __restrict__ w3,
    const float* __restrict__ b3, const float* __restrict__ p3,
    const float* __restrict__ wa, const float* __restrict__ ba,
    u64* __restrict__ cand, int* __restrict__ counter)
{
    __shared__ double sw[4608];   // [c][o][9]
    __shared__ double sb[32], sp[32], swa[64], sba[2];
    int t = threadIdx.y * 64 + threadIdx.x;
    for (int i = t; i < 4608; i += 256) {
        int o = i / 144, rem = i % 144, c = rem / 9, k = rem % 9;
        sw[(c * 32 + o) * 9 + k] = (double)w3[i];
    }
    if (t < 32) { sb[t] = (double)b3[t]; sp[t] = (double)p3[t]; }
    if (t < 64) swa[t] = (double)wa[t];
    if (t < 2)  sba[t] = (double)ba[t];
    __syncthreads();
    int px0 = blockIdx.x * 128 + threadIdx.x;
    int px1 = px0 + 64;
    int py = blockIdx.y * 4 + threadIdx.y;
    if (px0 >= W3H || py >= W3H) return;
    bool has1 = (px1 < W3H);
    double acc0[32], acc1[32];
    #pragma unroll
    for (int o = 0; o < 32; ++o) { acc0[o] = 0.0; acc1[o] = 0.0; }
    for (int c = 0; c < 16; ++c) {
        double in0[9], in1[9];
        #pragma unroll
        for (int u = 0; u < 3; ++u) {
            const double* row = H2 + ((size_t)c * W2H + py + u) * W2H + px0;
            in0[u * 3] = row[0]; in0[u * 3 + 1] = row[1]; in0[u * 3 + 2] = row[2];
            if (has1) { in1[u * 3] = row[64]; in1[u * 3 + 1] = row[65]; in1[u * 3 + 2] = row[66]; }
        }
        const double* wc = sw + c * 288;
        #pragma unroll
        for (int o = 0; o < 32; ++o) {
            const double* wp = wc + o * 9;
            double s = acc0[o];
            #pragma unroll
            for (int k = 0; k < 9; ++k) s = fma(in0[k], wp[k], s);
            acc0[o] = s;
            if (has1) {
                double q = acc1[o];
                #pragma unroll
                for (int k = 0; k < 9; ++k) q = fma(in1[k], wp[k], q);
                acc1[o] = q;
            }
        }
    }
    for (int pix = 0; pix < 2; ++pix) {
        if (pix == 1 && !has1) break;
        double* acc = (pix == 0) ? acc0 : acc1;
        int px = (pix == 0) ? px0 : px1;
        double c0 = sba[0], c1 = sba[1];
        #pragma unroll
        for (int o = 0; o < 32; ++o) {
            double v = acc[o] + sb[o];
            v = v >= 0.0 ? v : sp[o] * v;
            c0 = fma(swa[o], v, c0);
            c1 = fma(swa[32 + o], v, c1);
        }
        // prob >= 0.6 <=> c1-c0 >= ln(1.5)=0.405465...; 0.405 = safe prefilter
        if (c1 - c0 > 0.405) {
            double mx = fmax(c0, c1);
            double e0 = exp(c0 - mx), e1 = exp(c1 - mx);
            double prob = e1 / (e0 + e1);
            if (prob >= 0.6) {
                int slot = atomicAdd(counter, 1);
                if (slot < NPIX) {
                    u32 idx = (u32)(py * W3H + px);
                    // prob in [0.6,1]: bits-0x3FE0.. in [0,2^52]; keep top 44 bits (2^-43 rank granularity)
                    u64 bits = (u64)__double_as_longlong(prob);
                    u64 kh = (bits - 0x3FE0000000000000ull) >> 9;
                    cand[slot] = (kh << 20) | ((u64)(~idx) & IDXMASK);
                }
            }
        }
    }
}

__global__ void k_zero(int* c) { if (threadIdx.x == 0) *c = 0; }

// ------- pass B: each block sorts 4 chunks of 512, keeps local top-512 (desc) -------
__global__ __launch_bounds__(512) void k_sortchunks(
    const u64* __restrict__ cand, const int* __restrict__ counter,
    u64* __restrict__ sorted)
{
    __shared__ u64 stop_[512];
    __shared__ u64 schunk[512];
    int tid = threadIdx.x;
    int n = *counter; if (n > NPIX) n = NPIX;
    long base0 = (long)blockIdx.x * 2048;
    stop_[tid] = 0ull;
    if (base0 < n) {
        for (int s = 0; s < 4; ++s) {
            long base = base0 + (long)s * 512;
            if (base >= n) break;                 // uniform per block
            schunk[tid] = (base + tid < n) ? cand[base + tid] : 0ull;
            for (int k = 2; k <= 512; k <<= 1)
                for (int j = k >> 1; j > 0; j >>= 1) {
                    __syncthreads();
                    int ixj = tid ^ j;
                    if (ixj > tid) {
                        u64 a = schunk[tid], b = schunk[ixj];
                        bool desc = ((tid & k) == 0);
                        if (desc ? (a < b) : (a > b)) { schunk[tid] = b; schunk[ixj] = a; }
                    }
                }
            __syncthreads();
            // top-512 of union: elementwise max vs reversed chunk -> bitonic -> merge desc
            u64 m = stop_[tid], v = schunk[511 - tid];
            stop_[tid] = m > v ? m : v;
            for (int j = 256; j > 0; j >>= 1) {
                __syncthreads();
                int ixj = tid ^ j;
                if (ixj > tid) {
                    u64 a = stop_[tid], b = stop_[ixj];
                    if (a < b) { stop_[tid] = b; stop_[ixj] = a; }
                }
            }
            __syncthreads();
        }
    }
    sorted[(size_t)blockIdx.x * 512 + tid] = stop_[tid];   // zeros when no data
}

// ------- generic merge of 8 consecutive sorted-512 lists -> one sorted-512 -------
__global__ __launch_bounds__(512) void k_merge8(
    const u64* __restrict__ in, u64* __restrict__ out, int nin)
{
    __shared__ u64 s[512];
    int tid = threadIdx.x;
    int base = blockIdx.x * 8;
    s[tid] = (base < nin) ? in[(size_t)base * 512 + tid] : 0ull;
    for (int c = 1; c < 8; ++c) {
        int li = base + c;
        u64 v = (li < nin) ? in[(size_t)li * 512 + (511 - tid)] : 0ull;
        __syncthreads();
        u64 m = s[tid];
        s[tid] = m > v ? m : v;
        for (int j = 256; j > 0; j >>= 1) {
            __syncthreads();
            int ixj = tid ^ j;
            if (ixj > tid) {
                u64 a = s[tid], b = s[ixj];
                if (a < b) { s[tid] = b; s[ixj] = a; }
            }
        }
        __syncthreads();
    }
    out[(size_t)blockIdx.x * 512 + tid] = s[tid];
}

// ------- final: merge 8 lists; reg head recompute; boxes; 2x NMS (matrix+scan) -------
__global__ __launch_bounds__(512) void k_final(
    const u64* __restrict__ lists,
    const double* __restrict__ H2,
    const float* __restrict__ w3, const float* __restrict__ b3, const float* __restrict__ p3,
    const float* __restrict__ wb, const float* __restrict__ bb,
    float* __restrict__ out)
{
    __shared__ u64 stop_[512];
    __shared__ __align__(16) char arena[53248];   // phase1: sw f64[4608]=36864B; phase2: mat u64[4096]=32768B + boxes 20480B
    __shared__ double sb3[32], sp3[32], swb[128], sbb[4];
    __shared__ u64 keepw[8];

    int tid = threadIdx.x;
    double* sw = (double*)arena;
    for (int i = tid; i < 4608; i += 512) sw[i] = (double)w3[i];
    if (tid < 32) { sb3[tid] = (double)b3[tid]; sp3[tid] = (double)p3[tid]; }
    if (tid < 128) swb[tid] = (double)wb[tid];
    if (tid < 4)   sbb[tid] = (double)bb[tid];
    stop_[tid] = 0ull;
    __syncthreads();

    // merge the 8 level-2 lists
    for (int cb = 0; cb < 8; ++cb) {
        u64 v = lists[(size_t)cb * 512 + (511 - tid)];
        u64 m = stop_[tid];
        stop_[tid] = m > v ? m : v;
        for (int j = 256; j > 0; j >>= 1) {
            __syncthreads();
            int ixj = tid ^ j;
            if (ixj > tid) {
                u64 a = stop_[tid], b = stop_[ixj];
                if (a < b) { stop_[tid] = b; stop_[ixj] = a; }
            }
        }
        __syncthreads();
    }

    u64 key = stop_[tid];
    bool valid = key != 0ull;
    u32 idx = valid ? (u32)(IDXMASK - (key & IDXMASK)) : 0u;
    double score = 0.0;
    if (valid) {
        u64 bits = ((key >> 20) << 9) + 0x3FE0000000000000ull;  // prob truncated to 2^-43
        score = __longlong_as_double((long long)bits);
    }
    int yy = (int)(idx / W3H), xx = (int)(idx % W3H);

    // reg head recompute for winners (uses sw)
    double r0 = 0.0, r1 = 0.0, r2 = 0.0, r3 = 0.0;
    if (valid) {
        double acc[32];
        #pragma unroll
        for (int o = 0; o < 32; ++o) acc[o] = 0.0;
        for (int c = 0; c < 16; ++c) {
            double in[9];
            #pragma unroll
            for (int u = 0; u < 3; ++u) {
                const double* row = H2 + ((size_t)c * W2H + yy + u) * W2H + xx;
                in[u * 3] = row[0]; in[u * 3 + 1] = row[1]; in[u * 3 + 2] = row[2];
            }
            #pragma unroll
            for (int o = 0; o < 32; ++o) {
                const double* wp = sw + (o * 16 + c) * 9;
                double s = acc[o];
                #pragma unroll
                for (int k2 = 0; k2 < 9; ++k2) s = fma(in[k2], wp[k2], s);
                acc[o] = s;
            }
        }
        r0 = sbb[0]; r1 = sbb[1]; r2 = sbb[2]; r3 = sbb[3];
        #pragma unroll
        for (int o = 0; o < 32; ++o) {
            double v = acc[o] + sb3[o];
            v = v >= 0.0 ? v : sp3[o] * v;
            r0 = fma(swb[o], v, r0);
            r1 = fma(swb[32 + o], v, r1);
            r2 = fma(swb[64 + o], v, r2);
            r3 = fma(swb[96 + o], v, r3);
        }
    }
    __syncthreads();   // sw dead; re-purpose arena

    u64*    mat   = (u64*)arena;              // 32768 B
    double* bx1   = (double*)(arena + 32768); // 4 box arrays + area = 20480 B
    double* by1   = bx1 + 512;
    double* bx2   = bx1 + 1024;
    double* by2   = bx1 + 1536;
    double* sarea = bx1 + 2048;

    double fx = (double)xx, fy = (double)yy;
    double cx = (fx * 2.0 + 6.0) / 0.6;
    double cy = (fy * 2.0 + 6.0) / 0.6;
    double ww = 12.0 / 0.6;
    double hw = ww / 2.0;
    double x1 = cx - hw + r0 * ww;
    double y1 = cy - hw + r1 * ww;
    double x2 = cx + hw + r2 * ww;
    double y2 = cy + hw + r3 * ww;
    double area = (x2 - x1) * (y2 - y1);
    bx1[tid] = x1; by1[tid] = y1; bx2[tid] = x2; by2[tid] = y2;
    sarea[tid] = area;

    u64 bal = __ballot(valid);
    if ((tid & 63) == 0) keepw[tid >> 6] = bal;
    __syncthreads();

    for (int pass = 0; pass < 2; ++pass) {
        double thr = (pass == 0) ? 0.5 : 0.7;
        // build suppression bit-matrix: row i, bit j set iff (iou(i,j)>thr && j>i)
        u64 accw = 0;
        for (int j = 0; j < 512; ++j) {
            double ix1 = fmax(x1, bx1[j]);
            double iy1 = fmax(y1, by1[j]);
            double ix2 = fmin(x2, bx2[j]);
            double iy2 = fmin(y2, by2[j]);
            double inter = fmax(ix2 - ix1, 0.0) * fmax(iy2 - iy1, 0.0);
            double uni = area + sarea[j] - inter + 1e-9;
            // inter/uni > thr  <=>  (uni>0 && inter > thr*uni); uni<=0 => iou<=0 or nan => false
            bool sup = (uni > 0.0) && (inter > thr * uni) && (j > tid);
            accw |= ((u64)sup) << (j & 63);
            if ((j & 63) == 63) { mat[tid * 8 + (j >> 6)] = accw; accw = 0; }
        }
        __syncthreads();
        // greedy scan, single wave, no barriers in the chain
        if (tid < 64) {
            u64 kw = (tid < 8) ? keepw[tid] : 0ull;
            for (int i = 0; i < 512; ++i) {
                u64 row = mat[i * 8 + (tid & 7)];          // prefetch unconditional
                u64 cur = __shfl(kw, i >> 6);
                if ((cur >> (i & 63)) & 1) kw &= ~row;
            }
            if (tid < 8) keepw[tid] = kw;
        }
        __syncthreads();
    }

    double kf = ((keepw[tid >> 6] >> (tid & 63)) & 1) ? 1.0 : 0.0;
    out[tid * 5 + 0] = (float)(x1 * kf);
    out[tid * 5 + 1] = (float)(y1 * kf);
    out[tid * 5 + 2] = (float)(x2 * kf);
    out[tid * 5 + 3] = (float)(y2 * kf);
    out[tid * 5 + 4] = (float)(score * kf);
}

extern "C" void kernel_launch(void* const* d_in, const int* in_sizes, int n_in,
                              void* d_out, int out_size, void* d_ws, size_t ws_size,
                              hipStream_t stream)
{
    const float* x  = (const float*)d_in[0];
    const float* w1 = (const float*)d_in[1];
    const float* b1 = (const float*)d_in[2];
    const float* p1 = (const float*)d_in[3];
    const float* w2 = (const float*)d_in[4];
    const float* b2 = (const float*)d_in[5];
    const float* p2 = (const float*)d_in[6];
    const float* w3 = (const float*)d_in[7];
    const float* b3 = (const float*)d_in[8];
    const float* p3 = (const float*)d_in[9];
    const float* wa = (const float*)d_in[10];
    const float* ba = (const float*)d_in[11];
    const float* wb = (const float*)d_in[12];
    const float* bb = (const float*)d_in[13];
    float* out = (float*)d_out;

    char* ws = (char*)d_ws;
    double* P      = (double*)(ws);                    // 10*1023^2*8 = 83,722,320 B
    double* H2     = (double*)(ws + 83722496);         // 16*1021^2*8 = 133,432,448 B
    int*    counter= (int*)   (ws + 217154944);
    u64*    cand   = (u64*)   (ws + 217155200);        // NPIX*8 = 8,306,888 B
    u64*    sorted = (u64*)   (ws + 225462272);        // 508*512*8 = 2,080,768 B
    // l1out/l2out alias the cand region (cand fully consumed by k_sortchunks before these are written)
    u64*    l1out  = (u64*)   (ws + 217155200);        // 64*512*8 = 262,144 B
    u64*    l2out  = (u64*)   (ws + 217155200 + 262144); // 8*512*8 = 32,768 B

    k_zero<<<1, 64, 0, stream>>>(counter);
    k_conv1<<<dim3(16, 256), dim3(64, 4), 0, stream>>>(x, w1, b1, p1, P);
    k_conv2<<<dim3(8, 256),  dim3(64, 4), 0, stream>>>(P, w2, b2, p2, H2);
    k_conv3<<<dim3(8, 255),  dim3(64, 4), 0, stream>>>(H2, w3, b3, p3, wa, ba, cand, counter);
    k_sortchunks<<<508, 512, 0, stream>>>(cand, counter, sorted);
    k_merge8<<<64, 512, 0, stream>>>(sorted, l1out, 508);
    k_merge8<<<8, 512, 0, stream>>>(l1out, l2out, 64);
    k_final<<<1, 512, 0, stream>>>(l2out, H2, w3, b3, p3, wb, bb, out);
}

// Round 5
// 1029.082 us; speedup vs baseline: 5.3234x; 5.3234x over previous
//
#include <hip/hip_runtime.h>

typedef unsigned long long u64;
typedef unsigned int u32;

#define W1H 1023   // after conv1+pool
#define W2H 1021   // after conv2
#define W3H 1019   // after conv3
#define NPIX (W3H * W3H)          // 1,038,361 < 2^20
#define IDXMASK 0xFFFFFull

// f64 weight arena offsets (in doubles)
#define W1OFF 0
#define B1OFF 270
#define P1OFF 280
#define W2OFF 290
#define B2OFF 1730
#define P2OFF 1746
#define W3OFF 1762
#define B3OFF 6370
#define P3OFF 6402
#define WAOFF 6434
#define BAOFF 6498
#define WBOFF 6500
#define BBOFF 6628
#define WDTOT 6632

// ---- prep: convert all weights/biases/prelu to f64 once; zero counter ----
__global__ __launch_bounds__(256) void k_prep(
    const float* __restrict__ w1, const float* __restrict__ b1, const float* __restrict__ p1,
    const float* __restrict__ w2, const float* __restrict__ b2, const float* __restrict__ p2,
    const float* __restrict__ w3, const float* __restrict__ b3, const float* __restrict__ p3,
    const float* __restrict__ wa, const float* __restrict__ ba,
    const float* __restrict__ wb, const float* __restrict__ bb,
    double* __restrict__ wd, int* __restrict__ counter)
{
    int t = threadIdx.x;
    if (t == 0) *counter = 0;
    for (int i = t; i < 270; i += 256)  wd[W1OFF + i] = (double)w1[i];
    if (t < 10) { wd[B1OFF + t] = (double)b1[t]; wd[P1OFF + t] = (double)p1[t]; }
    for (int i = t; i < 1440; i += 256) wd[W2OFF + i] = (double)w2[i];
    if (t < 16) { wd[B2OFF + t] = (double)b2[t]; wd[P2OFF + t] = (double)p2[t]; }
    for (int i = t; i < 4608; i += 256) wd[W3OFF + i] = (double)w3[i];
    if (t < 32) { wd[B3OFF + t] = (double)b3[t]; wd[P3OFF + t] = (double)p3[t]; }
    if (t < 64)  wd[WAOFF + t] = (double)wa[t];
    if (t < 2)   wd[BAOFF + t] = (double)ba[t];
    if (t < 128) wd[WBOFF + t] = (double)wb[t];
    if (t < 4)   wd[BBOFF + t] = (double)bb[t];
}

// ---------------- conv1 (3->10, 3x3) + bias + prelu + maxpool2, f64 ----------------
// Weights via wave-uniform global reads (scalar path), no LDS.
__global__ __launch_bounds__(256) void k_conv1(
    const float* __restrict__ x, const double* __restrict__ wd,
    double* __restrict__ P)
{
    int px = blockIdx.x * 64 + threadIdx.x;
    int py = blockIdx.y * 4 + threadIdx.y;
    if (px >= W1H || py >= W1H) return;
    int ix = px * 2, iy = py * 2;
    double acc[10][4];
    #pragma unroll
    for (int ch = 0; ch < 10; ++ch) {
        acc[ch][0] = 0.0; acc[ch][1] = 0.0; acc[ch][2] = 0.0; acc[ch][3] = 0.0;
    }
    for (int c = 0; c < 3; ++c) {
        double in[4][4];
        #pragma unroll
        for (int u = 0; u < 4; ++u) {
            const float* row = x + ((size_t)c * 2048 + (iy + u)) * 2048 + ix;
            in[u][0] = (double)row[0]; in[u][1] = (double)row[1];
            in[u][2] = (double)row[2]; in[u][3] = (double)row[3];
        }
        #pragma unroll
        for (int ch = 0; ch < 10; ++ch) {
            const double* wp = wd + W1OFF + (ch * 3 + c) * 9;
            #pragma unroll
            for (int u = 0; u < 3; ++u)
                #pragma unroll
                for (int v = 0; v < 3; ++v) {
                    double w = wp[u * 3 + v];
                    acc[ch][0] = fma(in[u][v],         w, acc[ch][0]);
                    acc[ch][1] = fma(in[u][v + 1],     w, acc[ch][1]);
                    acc[ch][2] = fma(in[u + 1][v],     w, acc[ch][2]);
                    acc[ch][3] = fma(in[u + 1][v + 1], w, acc[ch][3]);
                }
        }
    }
    #pragma unroll
    for (int ch = 0; ch < 10; ++ch) {
        double m = fmax(fmax(acc[ch][0], acc[ch][1]), fmax(acc[ch][2], acc[ch][3])) + wd[B1OFF + ch];
        double r = m >= 0.0 ? m : wd[P1OFF + ch] * m;
        P[((size_t)ch * W1H + py) * W1H + px] = r;
    }
}

// ---------------- conv2 (10->16, 3x3) + bias + prelu, f64, 1px/thread ----------------
__global__ __launch_bounds__(256) void k_conv2(
    const double* __restrict__ P, const double* __restrict__ wd,
    double* __restrict__ H2)
{
    int px = blockIdx.x * 64 + threadIdx.x;
    int py = blockIdx.y * 4 + threadIdx.y;
    if (px >= W2H || py >= W2H) return;
    double acc[16];
    #pragma unroll
    for (int o = 0; o < 16; ++o) acc[o] = 0.0;
    for (int c = 0; c < 10; ++c) {
        double in[9];
        #pragma unroll
        for (int u = 0; u < 3; ++u) {
            const double* row = P + ((size_t)c * W1H + py + u) * W1H + px;
            in[u * 3] = row[0]; in[u * 3 + 1] = row[1]; in[u * 3 + 2] = row[2];
        }
        #pragma unroll
        for (int o = 0; o < 16; ++o) {
            const double* wp = wd + W2OFF + (o * 10 + c) * 9;   // raw OIHW layout, uniform
            double s = acc[o];
            #pragma unroll
            for (int k = 0; k < 9; ++k) s = fma(in[k], wp[k], s);
            acc[o] = s;
        }
    }
    #pragma unroll
    for (int o = 0; o < 16; ++o) {
        double v = acc[o] + wd[B2OFF + o];
        v = v >= 0.0 ? v : wd[P2OFF + o] * v;
        H2[((size_t)o * W2H + py) * W2H + px] = v;
    }
}

// ------- conv3 (16->32) + prelu + cls head + softmax + candidate push, f64, 1px -------
__global__ __launch_bounds__(256) void k_conv3(
    const double* __restrict__ H2, const double* __restrict__ wd,
    u64* __restrict__ cand, int* __restrict__ counter)
{
    int px = blockIdx.x * 64 + threadIdx.x;
    int py = blockIdx.y * 4 + threadIdx.y;
    if (px >= W3H || py >= W3H) return;
    double acc[32];
    #pragma unroll
    for (int o = 0; o < 32; ++o) acc[o] = 0.0;
    for (int c = 0; c < 16; ++c) {
        double in[9];
        #pragma unroll
        for (int u = 0; u < 3; ++u) {
            const double* row = H2 + ((size_t)c * W2H + py + u) * W2H + px;
            in[u * 3] = row[0]; in[u * 3 + 1] = row[1]; in[u * 3 + 2] = row[2];
        }
        #pragma unroll
        for (int o = 0; o < 32; ++o) {
            const double* wp = wd + W3OFF + (o * 16 + c) * 9;   // raw OIHW layout, uniform
            double s = acc[o];
            #pragma unroll
            for (int k = 0; k < 9; ++k) s = fma(in[k], wp[k], s);
            acc[o] = s;
        }
    }
    double c0 = wd[BAOFF + 0], c1 = wd[BAOFF + 1];
    #pragma unroll
    for (int o = 0; o < 32; ++o) {
        double v = acc[o] + wd[B3OFF + o];
        v = v >= 0.0 ? v : wd[P3OFF + o] * v;
        c0 = fma(wd[WAOFF + o], v, c0);
        c1 = fma(wd[WAOFF + 32 + o], v, c1);
    }
    // prob >= 0.6 <=> c1-c0 >= ln(1.5)=0.405465...; 0.405 = safe prefilter
    if (c1 - c0 > 0.405) {
        double mx = fmax(c0, c1);
        double e0 = exp(c0 - mx), e1 = exp(c1 - mx);
        double prob = e1 / (e0 + e1);
        if (prob >= 0.6) {
            int slot = atomicAdd(counter, 1);
            if (slot < NPIX) {
                u32 idx = (u32)(py * W3H + px);
                // prob in [0.6,1]: bits-0x3FE0.. in [0,2^52]; keep top 44 bits (2^-43 rank granularity)
                u64 bits = (u64)__double_as_longlong(prob);
                u64 kh = (bits - 0x3FE0000000000000ull) >> 9;
                cand[slot] = (kh << 20) | ((u64)(~idx) & IDXMASK);
            }
        }
    }
}

// ------- pass B: each block sorts 4 chunks of 512, keeps local top-512 (desc) -------
__global__ __launch_bounds__(512) void k_sortchunks(
    const u64* __restrict__ cand, const int* __restrict__ counter,
    u64* __restrict__ sorted)
{
    __shared__ u64 stop_[512];
    __shared__ u64 schunk[512];
    int tid = threadIdx.x;
    int n = *counter; if (n > NPIX) n = NPIX;
    long base0 = (long)blockIdx.x * 2048;
    stop_[tid] = 0ull;
    if (base0 < n) {
        for (int s = 0; s < 4; ++s) {
            long base = base0 + (long)s * 512;
            if (base >= n) break;                 // uniform per block
            schunk[tid] = (base + tid < n) ? cand[base + tid] : 0ull;
            for (int k = 2; k <= 512; k <<= 1)
                for (int j = k >> 1; j > 0; j >>= 1) {
                    __syncthreads();
                    int ixj = tid ^ j;
                    if (ixj > tid) {
                        u64 a = schunk[tid], b = schunk[ixj];
                        bool desc = ((tid & k) == 0);
                        if (desc ? (a < b) : (a > b)) { schunk[tid] = b; schunk[ixj] = a; }
                    }
                }
            __syncthreads();
            // top-512 of union: elementwise max vs reversed chunk -> bitonic -> merge desc
            u64 m = stop_[tid], v = schunk[511 - tid];
            stop_[tid] = m > v ? m : v;
            for (int j = 256; j > 0; j >>= 1) {
                __syncthreads();
                int ixj = tid ^ j;
                if (ixj > tid) {
                    u64 a = stop_[tid], b = stop_[ixj];
                    if (a < b) { stop_[tid] = b; stop_[ixj] = a; }
                }
            }
            __syncthreads();
        }
    }
    sorted[(size_t)blockIdx.x * 512 + tid] = stop_[tid];   // zeros when no data
}

// ------- generic merge of 8 consecutive sorted-512 lists -> one sorted-512 -------
__global__ __launch_bounds__(512) void k_merge8(
    const u64* __restrict__ in, u64* __restrict__ out, int nin)
{
    __shared__ u64 s[512];
    int tid = threadIdx.x;
    int base = blockIdx.x * 8;
    s[tid] = (base < nin) ? in[(size_t)base * 512 + tid] : 0ull;
    for (int c = 1; c < 8; ++c) {
        int li = base + c;
        u64 v = (li < nin) ? in[(size_t)li * 512 + (511 - tid)] : 0ull;
        __syncthreads();
        u64 m = s[tid];
        s[tid] = m > v ? m : v;
        for (int j = 256; j > 0; j >>= 1) {
            __syncthreads();
            int ixj = tid ^ j;
            if (ixj > tid) {
                u64 a = s[tid], b = s[ixj];
                if (a < b) { s[tid] = b; s[ixj] = a; }
            }
        }
        __syncthreads();
    }
    out[(size_t)blockIdx.x * 512 + tid] = s[tid];
}

// ------- final: merge 8 lists; reg head recompute; boxes; 2x NMS (matrix+scan) -------
__global__ __launch_bounds__(512) void k_final(
    const u64* __restrict__ lists,
    const double* __restrict__ H2, const double* __restrict__ wd,
    float* __restrict__ out)
{
    __shared__ u64 stop_[512];
    __shared__ __align__(16) char arena[53248];   // mat u64[4096]=32768B + boxes 20480B
    __shared__ u64 keepw[8];

    int tid = threadIdx.x;
    stop_[tid] = 0ull;
    __syncthreads();

    // merge the 8 level-2 lists
    for (int cb = 0; cb < 8; ++cb) {
        u64 v = lists[(size_t)cb * 512 + (511 - tid)];
        u64 m = stop_[tid];
        stop_[tid] = m > v ? m : v;
        for (int j = 256; j > 0; j >>= 1) {
            __syncthreads();
            int ixj = tid ^ j;
            if (ixj > tid) {
                u64 a = stop_[tid], b = stop_[ixj];
                if (a < b) { stop_[tid] = b; stop_[ixj] = a; }
            }
        }
        __syncthreads();
    }

    u64 key = stop_[tid];
    bool valid = key != 0ull;
    u32 idx = valid ? (u32)(IDXMASK - (key & IDXMASK)) : 0u;
    double score = 0.0;
    if (valid) {
        u64 bits = ((key >> 20) << 9) + 0x3FE0000000000000ull;  // prob truncated to 2^-43
        score = __longlong_as_double((long long)bits);
    }
    int yy = (int)(idx / W3H), xx = (int)(idx % W3H);

    // reg head recompute (unconditional: invalid threads use idx=0, result zeroed later)
    double acc[32];
    #pragma unroll
    for (int o = 0; o < 32; ++o) acc[o] = 0.0;
    for (int c = 0; c < 16; ++c) {
        double in[9];
        #pragma unroll
        for (int u = 0; u < 3; ++u) {
            const double* row = H2 + ((size_t)c * W2H + yy + u) * W2H + xx;
            in[u * 3] = row[0]; in[u * 3 + 1] = row[1]; in[u * 3 + 2] = row[2];
        }
        #pragma unroll
        for (int o = 0; o < 32; ++o) {
            const double* wp = wd + W3OFF + (o * 16 + c) * 9;
            double s = acc[o];
            #pragma unroll
            for (int k2 = 0; k2 < 9; ++k2) s = fma(in[k2], wp[k2], s);
            acc[o] = s;
        }
    }
    double r0 = wd[BBOFF + 0], r1 = wd[BBOFF + 1], r2 = wd[BBOFF + 2], r3 = wd[BBOFF + 3];
    #pragma unroll
    for (int o = 0; o < 32; ++o) {
        double v = acc[o] + wd[B3OFF + o];
        v = v >= 0.0 ? v : wd[P3OFF + o] * v;
        r0 = fma(wd[WBOFF + o], v, r0);
        r1 = fma(wd[WBOFF + 32 + o], v, r1);
        r2 = fma(wd[WBOFF + 64 + o], v, r2);
        r3 = fma(wd[WBOFF + 96 + o], v, r3);
    }

    u64*    mat   = (u64*)arena;              // 32768 B
    double* bx1   = (double*)(arena + 32768); // 4 box arrays + area = 20480 B
    double* by1   = bx1 + 512;
    double* bx2   = bx1 + 1024;
    double* by2   = bx1 + 1536;
    double* sarea = bx1 + 2048;

    double fx = (double)xx, fy = (double)yy;
    double cx = (fx * 2.0 + 6.0) / 0.6;
    double cy = (fy * 2.0 + 6.0) / 0.6;
    double ww = 12.0 / 0.6;
    double hw = ww / 2.0;
    double x1 = cx - hw + r0 * ww;
    double y1 = cy - hw + r1 * ww;
    double x2 = cx + hw + r2 * ww;
    double y2 = cy + hw + r3 * ww;
    double area = (x2 - x1) * (y2 - y1);
    bx1[tid] = x1; by1[tid] = y1; bx2[tid] = x2; by2[tid] = y2;
    sarea[tid] = area;

    u64 bal = __ballot(valid);
    if ((tid & 63) == 0) keepw[tid >> 6] = bal;
    __syncthreads();

    for (int pass = 0; pass < 2; ++pass) {
        double thr = (pass == 0) ? 0.5 : 0.7;
        // build suppression bit-matrix: row i, bit j set iff (iou(i,j)>thr && j>i)
        u64 accw = 0;
        for (int j = 0; j < 512; ++j) {
            double ix1 = fmax(x1, bx1[j]);
            double iy1 = fmax(y1, by1[j]);
            double ix2 = fmin(x2, bx2[j]);
            double iy2 = fmin(y2, by2[j]);
            double inter = fmax(ix2 - ix1, 0.0) * fmax(iy2 - iy1, 0.0);
            double uni = area + sarea[j] - inter + 1e-9;
            // inter/uni > thr  <=>  (uni>0 && inter > thr*uni); uni<=0 => iou<=0 or nan => false
            bool sup = (uni > 0.0) && (inter > thr * uni) && (j > tid);
            accw |= ((u64)sup) << (j & 63);
            if ((j & 63) == 63) { mat[tid * 8 + (j >> 6)] = accw; accw = 0; }
        }
        __syncthreads();
        // greedy scan, single wave, no barriers in the chain
        if (tid < 64) {
            u64 kw = (tid < 8) ? keepw[tid] : 0ull;
            for (int i = 0; i < 512; ++i) {
                u64 row = mat[i * 8 + (tid & 7)];          // prefetch unconditional
                u64 cur = __shfl(kw, i >> 6);
                if ((cur >> (i & 63)) & 1) kw &= ~row;
            }
            if (tid < 8) keepw[tid] = kw;
        }
        __syncthreads();
    }

    double kf = ((keepw[tid >> 6] >> (tid & 63)) & 1) ? 1.0 : 0.0;
    out[tid * 5 + 0] = (float)(x1 * kf);
    out[tid * 5 + 1] = (float)(y1 * kf);
    out[tid * 5 + 2] = (float)(x2 * kf);
    out[tid * 5 + 3] = (float)(y2 * kf);
    out[tid * 5 + 4] = (float)(score * kf);
}

extern "C" void kernel_launch(void* const* d_in, const int* in_sizes, int n_in,
                              void* d_out, int out_size, void* d_ws, size_t ws_size,
                              hipStream_t stream)
{
    const float* x  = (const float*)d_in[0];
    const float* w1 = (const float*)d_in[1];
    const float* b1 = (const float*)d_in[2];
    const float* p1 = (const float*)d_in[3];
    const float* w2 = (const float*)d_in[4];
    const float* b2 = (const float*)d_in[5];
    const float* p2 = (const float*)d_in[6];
    const float* w3 = (const float*)d_in[7];
    const float* b3 = (const float*)d_in[8];
    const float* p3 = (const float*)d_in[9];
    const float* wa = (const float*)d_in[10];
    const float* ba = (const float*)d_in[11];
    const float* wb = (const float*)d_in[12];
    const float* bb = (const float*)d_in[13];
    float* out = (float*)d_out;

    char* ws = (char*)d_ws;
    double* P      = (double*)(ws);                    // 10*1023^2*8 = 83,722,320 B
    double* H2     = (double*)(ws + 83722496);         // 16*1021^2*8 = 133,432,448 B
    int*    counter= (int*)   (ws + 217154944);
    u64*    cand   = (u64*)   (ws + 217155200);        // NPIX*8 = 8,306,888 B
    u64*    sorted = (u64*)   (ws + 225462272);        // 508*512*8 = 2,080,768 B
    double* wd     = (double*)(ws + 227543040);        // WDTOT*8 = 53,056 B
    // l1out/l2out alias the cand region (cand fully consumed by k_sortchunks before these are written)
    u64*    l1out  = (u64*)   (ws + 217155200);        // 64*512*8 = 262,144 B
    u64*    l2out  = (u64*)   (ws + 217155200 + 262144); // 8*512*8 = 32,768 B

    k_prep<<<1, 256, 0, stream>>>(w1, b1, p1, w2, b2, p2, w3, b3, p3, wa, ba, wb, bb, wd, counter);
    k_conv1<<<dim3(16, 256), dim3(64, 4), 0, stream>>>(x, wd, P);
    k_conv2<<<dim3(16, 256), dim3(64, 4), 0, stream>>>(P, wd, H2);
    k_conv3<<<dim3(16, 255), dim3(64, 4), 0, stream>>>(H2, wd, cand, counter);
    k_sortchunks<<<508, 512, 0, stream>>>(cand, counter, sorted);
    k_merge8<<<64, 512, 0, stream>>>(sorted, l1out, 508);
    k_merge8<<<8, 512, 0, stream>>>(l1out, l2out, 64);
    k_final<<<1, 512, 0, stream>>>(l2out, H2, wd, out);
}

// Round 6
// 1001.429 us; speedup vs baseline: 5.4705x; 1.0276x over previous
//
#include <hip/hip_runtime.h>

typedef unsigned long long u64;
typedef unsigned int u32;

#define W1H 1023   // after conv1+pool
#define W2H 1021   // after conv2
#define W3H 1019   // after conv3
#define NPIX (W3H * W3H)          // 1,038,361 < 2^20
#define IDXMASK 0xFFFFFull

#define NBINS 2048
#define HLO 0.3055f      // ln(1.5) - 0.10
#define HW_ 0.025f       // bin width
#define HINV 40.0f       // 1/HW_
#define HDELTA 0.10f     // selection margin (>= 2*|f32-f64| logit error, ~30x)

// f64 weight arena offsets (in doubles)
#define W1OFF 0
#define B1OFF 270
#define P1OFF 280
#define W2OFF 290
#define B2OFF 1730
#define P2OFF 1746
#define W3OFF 1762
#define B3OFF 6370
#define P3OFF 6402
#define WAOFF 6434
#define BAOFF 6498
#define WBOFF 6500
#define BBOFF 6628
#define WDTOT 6632

// ---- prep: convert weights to f64; zero ctrl + hist ----
__global__ __launch_bounds__(256) void k_prep(
    const float* __restrict__ w1, const float* __restrict__ b1, const float* __restrict__ p1,
    const float* __restrict__ w2, const float* __restrict__ b2, const float* __restrict__ p2,
    const float* __restrict__ w3, const float* __restrict__ b3, const float* __restrict__ p3,
    const float* __restrict__ wa, const float* __restrict__ ba,
    const float* __restrict__ wb, const float* __restrict__ bb,
    double* __restrict__ wd, int* __restrict__ ctrl, u32* __restrict__ ghist)
{
    int t = threadIdx.x;
    if (t < 2) ctrl[t] = 0;
    for (int i = t; i < NBINS; i += 256) ghist[i] = 0u;
    for (int i = t; i < 270; i += 256)  wd[W1OFF + i] = (double)w1[i];
    if (t < 10) { wd[B1OFF + t] = (double)b1[t]; wd[P1OFF + t] = (double)p1[t]; }
    for (int i = t; i < 1440; i += 256) wd[W2OFF + i] = (double)w2[i];
    if (t < 16) { wd[B2OFF + t] = (double)b2[t]; wd[P2OFF + t] = (double)p2[t]; }
    for (int i = t; i < 4608; i += 256) wd[W3OFF + i] = (double)w3[i];
    if (t < 32) { wd[B3OFF + t] = (double)b3[t]; wd[P3OFF + t] = (double)p3[t]; }
    if (t < 64)  wd[WAOFF + t] = (double)wa[t];
    if (t < 2)   wd[BAOFF + t] = (double)ba[t];
    if (t < 128) wd[WBOFF + t] = (double)wb[t];
    if (t < 4)   wd[BBOFF + t] = (double)bb[t];
}

// ---------------- conv1 f32 (3->10) + bias + prelu + maxpool2 ----------------
__global__ __launch_bounds__(256) void k_conv1f(
    const float* __restrict__ x, const float* __restrict__ w1,
    const float* __restrict__ b1, const float* __restrict__ p1,
    float* __restrict__ P)
{
    __shared__ float sw[270];
    __shared__ float sb[10], sp[10];
    int t = threadIdx.y * 64 + threadIdx.x;
    for (int i = t; i < 270; i += 256) sw[i] = w1[i];
    if (t < 10) { sb[t] = b1[t]; sp[t] = p1[t]; }
    __syncthreads();
    int px = blockIdx.x * 64 + threadIdx.x;
    int py = blockIdx.y * 4 + threadIdx.y;
    if (px >= W1H || py >= W1H) return;
    int ix = px * 2, iy = py * 2;
    float acc[10][4];
    #pragma unroll
    for (int ch = 0; ch < 10; ++ch) { acc[ch][0]=0.f; acc[ch][1]=0.f; acc[ch][2]=0.f; acc[ch][3]=0.f; }
    for (int c = 0; c < 3; ++c) {
        float in[4][4];
        #pragma unroll
        for (int u = 0; u < 4; ++u) {
            const float* row = x + ((size_t)c * 2048 + (iy + u)) * 2048 + ix;
            in[u][0]=row[0]; in[u][1]=row[1]; in[u][2]=row[2]; in[u][3]=row[3];
        }
        #pragma unroll
        for (int ch = 0; ch < 10; ++ch) {
            const float* wp = sw + (ch * 3 + c) * 9;
            #pragma unroll
            for (int u = 0; u < 3; ++u)
                #pragma unroll
                for (int v = 0; v < 3; ++v) {
                    float w = wp[u * 3 + v];
                    acc[ch][0] = fmaf(in[u][v],         w, acc[ch][0]);
                    acc[ch][1] = fmaf(in[u][v + 1],     w, acc[ch][1]);
                    acc[ch][2] = fmaf(in[u + 1][v],     w, acc[ch][2]);
                    acc[ch][3] = fmaf(in[u + 1][v + 1], w, acc[ch][3]);
                }
        }
    }
    #pragma unroll
    for (int ch = 0; ch < 10; ++ch) {
        float m = fmaxf(fmaxf(acc[ch][0], acc[ch][1]), fmaxf(acc[ch][2], acc[ch][3])) + sb[ch];
        float r = m >= 0.f ? m : sp[ch] * m;
        P[((size_t)ch * W1H + py) * W1H + px] = r;
    }
}

// ---------------- conv2 f32 (10->16) + bias + prelu, 2px/thread ----------------
__global__ __launch_bounds__(256) void k_conv2f(
    const float* __restrict__ P, const float* __restrict__ w2,
    const float* __restrict__ b2, const float* __restrict__ p2,
    float* __restrict__ H2)
{
    __shared__ __align__(16) float sw[10 * 16 * 12]; // [c][o][12]
    __shared__ float sb[16], sp[16];
    int t = threadIdx.y * 64 + threadIdx.x;
    for (int i = t; i < 1440; i += 256) {
        int o = i / 90, r = i % 90, c = r / 9, k = r % 9;
        sw[(c * 16 + o) * 12 + k] = w2[i];
    }
    if (t < 16) { sb[t] = b2[t]; sp[t] = p2[t]; }
    __syncthreads();
    int px0 = blockIdx.x * 128 + threadIdx.x;
    int px1 = px0 + 64;
    int py = blockIdx.y * 4 + threadIdx.y;
    if (px0 >= W2H || py >= W2H) return;
    bool has1 = (px1 < W2H);
    float acc0[16], acc1[16];
    #pragma unroll
    for (int o = 0; o < 16; ++o) { acc0[o] = 0.f; acc1[o] = 0.f; }
    for (int c = 0; c < 10; ++c) {
        float in0[9], in1[9];
        #pragma unroll
        for (int u = 0; u < 3; ++u) {
            const float* row = P + ((size_t)c * W1H + py + u) * W1H + px0;
            in0[u*3]=row[0]; in0[u*3+1]=row[1]; in0[u*3+2]=row[2];
            if (has1) { in1[u*3]=row[64]; in1[u*3+1]=row[65]; in1[u*3+2]=row[66]; }
        }
        #pragma unroll
        for (int o = 0; o < 16; ++o) {
            const float4* wv = (const float4*)(sw + (c * 16 + o) * 12);
            float4 wA = wv[0], wB = wv[1], wC = wv[2];
            float s = acc0[o];
            s = fmaf(in0[0],wA.x,s); s = fmaf(in0[1],wA.y,s); s = fmaf(in0[2],wA.z,s);
            s = fmaf(in0[3],wA.w,s); s = fmaf(in0[4],wB.x,s); s = fmaf(in0[5],wB.y,s);
            s = fmaf(in0[6],wB.z,s); s = fmaf(in0[7],wB.w,s); s = fmaf(in0[8],wC.x,s);
            acc0[o] = s;
            if (has1) {
                float q = acc1[o];
                q = fmaf(in1[0],wA.x,q); q = fmaf(in1[1],wA.y,q); q = fmaf(in1[2],wA.z,q);
                q = fmaf(in1[3],wA.w,q); q = fmaf(in1[4],wB.x,q); q = fmaf(in1[5],wB.y,q);
                q = fmaf(in1[6],wB.z,q); q = fmaf(in1[7],wB.w,q); q = fmaf(in1[8],wC.x,q);
                acc1[o] = q;
            }
        }
    }
    #pragma unroll
    for (int o = 0; o < 16; ++o) {
        float v = acc0[o] + sb[o];
        v = v >= 0.f ? v : sp[o] * v;
        H2[((size_t)o * W2H + py) * W2H + px0] = v;
        if (has1) {
            float w = acc1[o] + sb[o];
            w = w >= 0.f ? w : sp[o] * w;
            H2[((size_t)o * W2H + py) * W2H + px1] = w;
        }
    }
}

// ------- conv3 f32 (16->32) + prelu + cls head: logit plane + fused histogram -------
__global__ __launch_bounds__(256) void k_conv3f(
    const float* __restrict__ H2, const float* __restrict__ w3,
    const float* __restrict__ b3, const float* __restrict__ p3,
    const float* __restrict__ wa, const float* __restrict__ ba,
    float* __restrict__ Lg, u32* __restrict__ ghist)
{
    __shared__ __align__(16) float sw[16 * 32 * 12]; // [c][o][12]
    __shared__ float sb[32], sp[32], swa[64], sba[2];
    __shared__ u32 hist[NBINS];
    int t = threadIdx.y * 64 + threadIdx.x;
    for (int i = t; i < 4608; i += 256) {
        int o = i / 144, rem = i % 144, c = rem / 9, k = rem % 9;
        sw[(c * 32 + o) * 12 + k] = w3[i];
    }
    if (t < 32) { sb[t] = b3[t]; sp[t] = p3[t]; }
    if (t < 64) swa[t] = wa[t];
    if (t < 2)  sba[t] = ba[t];
    for (int i = t; i < NBINS; i += 256) hist[i] = 0u;
    __syncthreads();

    int px0 = blockIdx.x * 128 + threadIdx.x;
    int px1 = px0 + 64;
    int py = blockIdx.y * 4 + threadIdx.y;
    if (py < W3H && px0 < W3H) {
        bool has1 = (px1 < W3H);
        float acc0[32], acc1[32];
        #pragma unroll
        for (int o = 0; o < 32; ++o) { acc0[o] = 0.f; acc1[o] = 0.f; }
        for (int c = 0; c < 16; ++c) {
            float in0[9], in1[9];
            #pragma unroll
            for (int u = 0; u < 3; ++u) {
                const float* row = H2 + ((size_t)c * W2H + py + u) * W2H + px0;
                in0[u*3]=row[0]; in0[u*3+1]=row[1]; in0[u*3+2]=row[2];
                if (has1) { in1[u*3]=row[64]; in1[u*3+1]=row[65]; in1[u*3+2]=row[66]; }
            }
            #pragma unroll
            for (int o = 0; o < 32; ++o) {
                const float4* wv = (const float4*)(sw + (c * 32 + o) * 12);
                float4 wA = wv[0], wB = wv[1], wC = wv[2];
                float s = acc0[o];
                s = fmaf(in0[0],wA.x,s); s = fmaf(in0[1],wA.y,s); s = fmaf(in0[2],wA.z,s);
                s = fmaf(in0[3],wA.w,s); s = fmaf(in0[4],wB.x,s); s = fmaf(in0[5],wB.y,s);
                s = fmaf(in0[6],wB.z,s); s = fmaf(in0[7],wB.w,s); s = fmaf(in0[8],wC.x,s);
                acc0[o] = s;
                if (has1) {
                    float q = acc1[o];
                    q = fmaf(in1[0],wA.x,q); q = fmaf(in1[1],wA.y,q); q = fmaf(in1[2],wA.z,q);
                    q = fmaf(in1[3],wA.w,q); q = fmaf(in1[4],wB.x,q); q = fmaf(in1[5],wB.y,q);
                    q = fmaf(in1[6],wB.z,q); q = fmaf(in1[7],wB.w,q); q = fmaf(in1[8],wC.x,q);
                    acc1[o] = q;
                }
            }
        }
        #pragma unroll
        for (int pix = 0; pix < 2; ++pix) {
            if (pix == 1 && !has1) break;
            float* acc = (pix == 0) ? acc0 : acc1;
            int px = (pix == 0) ? px0 : px1;
            float c0 = sba[0], c1 = sba[1];
            #pragma unroll
            for (int o = 0; o < 32; ++o) {
                float v = acc[o] + sb[o];
                v = v >= 0.f ? v : sp[o] * v;
                c0 = fmaf(swa[o], v, c0);
                c1 = fmaf(swa[32 + o], v, c1);
            }
            float lg = c1 - c0;
            Lg[py * W3H + px] = lg;
            if (lg >= HLO) {
                int bin = (int)((lg - HLO) * HINV);
                if (bin > NBINS - 1) bin = NBINS - 1;
                atomicAdd(&hist[bin], 1u);
            }
        }
    }
    __syncthreads();
    for (int i = t; i < NBINS; i += 256) {
        u32 v = hist[i];
        if (v) atomicAdd(&ghist[i], v);
    }
}

// ---- scan: find selection threshold Tsel from histogram (rank-512 from top) ----
__global__ __launch_bounds__(256) void k_scan(
    const u32* __restrict__ ghist, int* __restrict__ ctrl)
{
    __shared__ u32 h[NBINS];
    int t = threadIdx.x;
    for (int i = t; i < NBINS; i += 256) h[i] = ghist[i];
    __syncthreads();
    if (t == 0) {
        int cum = 0, bstar = -1;
        for (int b = NBINS - 1; b >= 0; --b) {
            cum += (int)h[b];
            if (cum >= 512) { bstar = b; break; }
        }
        float T = (bstar < 0) ? HLO : (HLO + (float)bstar * HW_ - HDELTA);
        ((float*)ctrl)[2] = T;
    }
}

// ---- select: pixels with f32 logit >= Tsel ----
__global__ __launch_bounds__(256) void k_select(
    const float* __restrict__ Lg, int* __restrict__ ctrl, u32* __restrict__ selidx)
{
    float T = ((const float*)ctrl)[2];
    int stride = gridDim.x * 256;
    for (int i = blockIdx.x * 256 + threadIdx.x; i < NPIX; i += stride) {
        if (Lg[i] >= T) {
            int slot = atomicAdd(&ctrl[0], 1);
            selidx[slot] = (u32)i;
        }
    }
}

// ---- recompute: exact f64 pyramid per selected pixel; emit key + boxes ----
__global__ __launch_bounds__(64) void k_recomp(
    const float* __restrict__ x, const double* __restrict__ wd,
    const u32* __restrict__ selidx, int* __restrict__ ctrl,
    u64* __restrict__ keys, double* __restrict__ boxplane)
{
    __shared__ double xw[3][12][12];
    __shared__ double Pw[10][5][5];
    __shared__ double Hw[16][3][3];
    __shared__ double vch[32];
    int nsel = ctrl[0]; if (nsel > NPIX) nsel = NPIX;
    int t = threadIdx.x;
    for (int s = blockIdx.x; s < nsel; s += gridDim.x) {
        u32 idx = selidx[s];
        int y3 = (int)(idx / W3H), x3 = (int)(idx % W3H);
        int xr = 2 * y3, xc = 2 * x3;
        for (int i = t; i < 432; i += 64) {
            int c = i / 144, r = (i % 144) / 12, cc = i % 12;
            xw[c][r][cc] = (double)x[((size_t)c * 2048 + (xr + r)) * 2048 + (xc + cc)];
        }
        __syncthreads();
        // conv1 + bias + prelu + maxpool: 10ch x 5x5 P window
        for (int i = t; i < 250; i += 64) {
            int ch = i / 25, py = (i % 25) / 5, px = i % 5;
            int r0 = py * 2, c0 = px * 2;
            double a00=0.0, a01=0.0, a10=0.0, a11=0.0;
            for (int c = 0; c < 3; ++c) {
                const double* wp = wd + W1OFF + (ch * 3 + c) * 9;
                #pragma unroll
                for (int u = 0; u < 3; ++u)
                    #pragma unroll
                    for (int v = 0; v < 3; ++v) {
                        double w = wp[u * 3 + v];
                        a00 = fma(xw[c][r0+u][c0+v],     w, a00);
                        a01 = fma(xw[c][r0+u][c0+v+1],   w, a01);
                        a10 = fma(xw[c][r0+u+1][c0+v],   w, a10);
                        a11 = fma(xw[c][r0+u+1][c0+v+1], w, a11);
                    }
            }
            double m = fmax(fmax(a00, a01), fmax(a10, a11)) + wd[B1OFF + ch];
            Pw[ch][py][px] = m >= 0.0 ? m : wd[P1OFF + ch] * m;
        }
        __syncthreads();
        // conv2 + bias + prelu: 16ch x 3x3 H2 window
        for (int i = t; i < 144; i += 64) {
            int o = i / 9, hy = (i % 9) / 3, hx = i % 3;
            double acc = 0.0;
            for (int c = 0; c < 10; ++c) {
                const double* wp = wd + W2OFF + (o * 10 + c) * 9;
                #pragma unroll
                for (int k = 0; k < 9; ++k)
                    acc = fma(Pw[c][hy + k / 3][hx + k % 3], wp[k], acc);
            }
            acc += wd[B2OFF + o];
            Hw[o][hy][hx] = acc >= 0.0 ? acc : wd[P2OFF + o] * acc;
        }
        __syncthreads();
        // conv3 + bias + prelu: 32 channels at center pixel
        if (t < 32) {
            double acc = 0.0;
            for (int c = 0; c < 16; ++c) {
                const double* wp = wd + W3OFF + (t * 16 + c) * 9;
                #pragma unroll
                for (int k = 0; k < 9; ++k)
                    acc = fma(Hw[c][k / 3][k % 3], wp[k], acc);
            }
            acc += wd[B3OFF + t];
            vch[t] = acc >= 0.0 ? acc : wd[P3OFF + t] * acc;
        }
        __syncthreads();
        if (t == 0) {
            double c0 = wd[BAOFF + 0], c1 = wd[BAOFF + 1];
            for (int o = 0; o < 32; ++o) {
                c0 = fma(wd[WAOFF + o], vch[o], c0);
                c1 = fma(wd[WAOFF + 32 + o], vch[o], c1);
            }
            double mx = fmax(c0, c1);
            double e0 = exp(c0 - mx), e1 = exp(c1 - mx);
            double prob = e1 / (e0 + e1);
            if (prob >= 0.6) {
                double r0 = wd[BBOFF+0], r1 = wd[BBOFF+1], r2 = wd[BBOFF+2], r3 = wd[BBOFF+3];
                for (int o = 0; o < 32; ++o) {
                    double v = vch[o];
                    r0 = fma(wd[WBOFF + o], v, r0);
                    r1 = fma(wd[WBOFF + 32 + o], v, r1);
                    r2 = fma(wd[WBOFF + 64 + o], v, r2);
                    r3 = fma(wd[WBOFF + 96 + o], v, r3);
                }
                double fx = (double)x3, fy = (double)y3;
                double cx = (fx * 2.0 + 6.0) / 0.6;
                double cy = (fy * 2.0 + 6.0) / 0.6;
                double ww = 12.0 / 0.6, hw = ww / 2.0;
                double* bp = boxplane + (size_t)idx * 5;
                bp[0] = cx - hw + r0 * ww;
                bp[1] = cy - hw + r1 * ww;
                bp[2] = cx + hw + r2 * ww;
                bp[3] = cy + hw + r3 * ww;
                bp[4] = prob;
                u64 bits = (u64)__double_as_longlong(prob);
                u64 kh = (bits - 0x3FE0000000000000ull) >> 9;
                int slot = atomicAdd(&ctrl[1], 1);
                keys[slot] = (kh << 20) | ((u64)(~idx) & IDXMASK);
            }
        }
        __syncthreads();
    }
}

// ------- pass B: each block sorts 4 chunks of 512, keeps local top-512 (desc) -------
__global__ __launch_bounds__(512) void k_sortchunks(
    const u64* __restrict__ cand, const int* __restrict__ ctrl,
    u64* __restrict__ sorted)
{
    __shared__ u64 stop_[512];
    __shared__ u64 schunk[512];
    int tid = threadIdx.x;
    int n = ctrl[1]; if (n > NPIX) n = NPIX;
    long base0 = (long)blockIdx.x * 2048;
    stop_[tid] = 0ull;
    if (base0 < n) {
        for (int s = 0; s < 4; ++s) {
            long base = base0 + (long)s * 512;
            if (base >= n) break;                 // uniform per block
            schunk[tid] = (base + tid < n) ? cand[base + tid] : 0ull;
            for (int k = 2; k <= 512; k <<= 1)
                for (int j = k >> 1; j > 0; j >>= 1) {
                    __syncthreads();
                    int ixj = tid ^ j;
                    if (ixj > tid) {
                        u64 a = schunk[tid], b = schunk[ixj];
                        bool desc = ((tid & k) == 0);
                        if (desc ? (a < b) : (a > b)) { schunk[tid] = b; schunk[ixj] = a; }
                    }
                }
            __syncthreads();
            u64 m = stop_[tid], v = schunk[511 - tid];
            stop_[tid] = m > v ? m : v;
            for (int j = 256; j > 0; j >>= 1) {
                __syncthreads();
                int ixj = tid ^ j;
                if (ixj > tid) {
                    u64 a = stop_[tid], b = stop_[ixj];
                    if (a < b) { stop_[tid] = b; stop_[ixj] = a; }
                }
            }
            __syncthreads();
        }
    }
    sorted[(size_t)blockIdx.x * 512 + tid] = stop_[tid];
}

// ------- merge 8 consecutive sorted-512 lists -> one sorted-512 -------
__global__ __launch_bounds__(512) void k_merge8(
    const u64* __restrict__ in, u64* __restrict__ out, int nin)
{
    __shared__ u64 s[512];
    int tid = threadIdx.x;
    int base = blockIdx.x * 8;
    s[tid] = (base < nin) ? in[(size_t)base * 512 + tid] : 0ull;
    for (int c = 1; c < 8; ++c) {
        int li = base + c;
        u64 v = (li < nin) ? in[(size_t)li * 512 + (511 - tid)] : 0ull;
        __syncthreads();
        u64 m = s[tid];
        s[tid] = m > v ? m : v;
        for (int j = 256; j > 0; j >>= 1) {
            __syncthreads();
            int ixj = tid ^ j;
            if (ixj > tid) {
                u64 a = s[tid], b = s[ixj];
                if (a < b) { s[tid] = b; s[ixj] = a; }
            }
        }
        __syncthreads();
    }
    out[(size_t)blockIdx.x * 512 + tid] = s[tid];
}

// ------- final: merge 8 lists; fetch exact boxes; 2x NMS (matrix+scan) -------
__global__ __launch_bounds__(512) void k_final(
    const u64* __restrict__ lists, const double* __restrict__ boxplane,
    float* __restrict__ out)
{
    __shared__ u64 stop_[512];
    __shared__ __align__(16) char arena[53248];   // mat u64[4096]=32768B + boxes 20480B
    __shared__ u64 keepw[8];

    int tid = threadIdx.x;
    stop_[tid] = 0ull;
    __syncthreads();

    for (int cb = 0; cb < 8; ++cb) {
        u64 v = lists[(size_t)cb * 512 + (511 - tid)];
        u64 m = stop_[tid];
        stop_[tid] = m > v ? m : v;
        for (int j = 256; j > 0; j >>= 1) {
            __syncthreads();
            int ixj = tid ^ j;
            if (ixj > tid) {
                u64 a = stop_[tid], b = stop_[ixj];
                if (a < b) { stop_[tid] = b; stop_[ixj] = a; }
            }
        }
        __syncthreads();
    }

    u64 key = stop_[tid];
    bool valid = key != 0ull;
    double x1 = 0.0, y1 = 0.0, x2 = 0.0, y2 = 0.0, score = 0.0;
    if (valid) {
        u32 idx = (u32)(IDXMASK - (key & IDXMASK));
        const double* bp = boxplane + (size_t)idx * 5;
        x1 = bp[0]; y1 = bp[1]; x2 = bp[2]; y2 = bp[3]; score = bp[4];
    }

    u64*    mat   = (u64*)arena;              // 32768 B
    double* bx1   = (double*)(arena + 32768);
    double* by1   = bx1 + 512;
    double* bx2   = bx1 + 1024;
    double* by2   = bx1 + 1536;
    double* sarea = bx1 + 2048;

    double area = (x2 - x1) * (y2 - y1);
    bx1[tid] = x1; by1[tid] = y1; bx2[tid] = x2; by2[tid] = y2;
    sarea[tid] = area;

    u64 bal = __ballot(valid);
    if ((tid & 63) == 0) keepw[tid >> 6] = bal;
    __syncthreads();

    for (int pass = 0; pass < 2; ++pass) {
        double thr = (pass == 0) ? 0.5 : 0.7;
        u64 accw = 0;
        for (int j = 0; j < 512; ++j) {
            double ix1 = fmax(x1, bx1[j]);
            double iy1 = fmax(y1, by1[j]);
            double ix2 = fmin(x2, bx2[j]);
            double iy2 = fmin(y2, by2[j]);
            double inter = fmax(ix2 - ix1, 0.0) * fmax(iy2 - iy1, 0.0);
            double uni = area + sarea[j] - inter + 1e-9;
            bool sup = (uni > 0.0) && (inter > thr * uni) && (j > tid);
            accw |= ((u64)sup) << (j & 63);
            if ((j & 63) == 63) { mat[tid * 8 + (j >> 6)] = accw; accw = 0; }
        }
        __syncthreads();
        if (tid < 64) {
            u64 kw = (tid < 8) ? keepw[tid] : 0ull;
            for (int i = 0; i < 512; ++i) {
                u64 row = mat[i * 8 + (tid & 7)];
                u64 cur = __shfl(kw, i >> 6);
                if ((cur >> (i & 63)) & 1) kw &= ~row;
            }
            if (tid < 8) keepw[tid] = kw;
        }
        __syncthreads();
    }

    double kf = ((keepw[tid >> 6] >> (tid & 63)) & 1) ? 1.0 : 0.0;
    out[tid * 5 + 0] = (float)(x1 * kf);
    out[tid * 5 + 1] = (float)(y1 * kf);
    out[tid * 5 + 2] = (float)(x2 * kf);
    out[tid * 5 + 3] = (float)(y2 * kf);
    out[tid * 5 + 4] = (float)(score * kf);
}

extern "C" void kernel_launch(void* const* d_in, const int* in_sizes, int n_in,
                              void* d_out, int out_size, void* d_ws, size_t ws_size,
                              hipStream_t stream)
{
    const float* x  = (const float*)d_in[0];
    const float* w1 = (const float*)d_in[1];
    const float* b1 = (const float*)d_in[2];
    const float* p1 = (const float*)d_in[3];
    const float* w2 = (const float*)d_in[4];
    const float* b2 = (const float*)d_in[5];
    const float* p2 = (const float*)d_in[6];
    const float* w3 = (const float*)d_in[7];
    const float* b3 = (const float*)d_in[8];
    const float* p3 = (const float*)d_in[9];
    const float* wa = (const float*)d_in[10];
    const float* ba = (const float*)d_in[11];
    const float* wb = (const float*)d_in[12];
    const float* bb = (const float*)d_in[13];
    float* out = (float*)d_out;

    char* ws = (char*)d_ws;
    float*  Pf    = (float*) (ws);                       // 10*1023^2*4 = 41,861,160
    float*  H2f   = (float*) (ws + 41861376);            // 16*1021^2*4 = 66,716,224
    float*  Lg    = (float*) (ws + 108577792);           // 1019^2*4    =  4,153,444
    u32*    ghist = (u32*)   (ws + 112731392);           // 2048*4
    int*    ctrl  = (int*)   (ws + 112739584);           // 256 B: [0]=selcnt [1]=emit [2]=Tsel(f32)
    u32*    selidx= (u32*)   (ws + 112739840);           // NPIX*4      =  4,153,444
    u64*    keys  = (u64*)   (ws + 116893440);           // NPIX*8      =  8,306,888
    u64*    sorted= (u64*)   (ws + 125200384);           // 508*512*8   =  2,080,768
    u64*    l1out = (u64*)   (ws + 127281152);           // 64*512*8    =    262,144
    u64*    l2out = (u64*)   (ws + 127543296);           // 8*512*8     =     32,768
    double* boxpl = (double*)(ws + 127576064);           // NPIX*5*8    = 41,534,440
    double* wd    = (double*)(ws + 169110656);           // WDTOT*8     =     53,056

    k_prep<<<1, 256, 0, stream>>>(w1, b1, p1, w2, b2, p2, w3, b3, p3, wa, ba, wb, bb, wd, ctrl, ghist);
    k_conv1f<<<dim3(16, 256), dim3(64, 4), 0, stream>>>(x, w1, b1, p1, Pf);
    k_conv2f<<<dim3(8, 256),  dim3(64, 4), 0, stream>>>(Pf, w2, b2, p2, H2f);
    k_conv3f<<<dim3(8, 255),  dim3(64, 4), 0, stream>>>(H2f, w3, b3, p3, wa, ba, Lg, ghist);
    k_scan<<<1, 256, 0, stream>>>(ghist, ctrl);
    k_select<<<1024, 256, 0, stream>>>(Lg, ctrl, selidx);
    k_recomp<<<2048, 64, 0, stream>>>(x, wd, selidx, ctrl, keys, boxpl);
    k_sortchunks<<<508, 512, 0, stream>>>(keys, ctrl, sorted);
    k_merge8<<<64, 512, 0, stream>>>(sorted, l1out, 508);
    k_merge8<<<8, 512, 0, stream>>>(l1out, l2out, 64);
    k_final<<<1, 512, 0, stream>>>(l2out, boxpl, out);
}

// Round 7
// 755.050 us; speedup vs baseline: 7.2555x; 1.3263x over previous
//
#include <hip/hip_runtime.h>

typedef unsigned long long u64;
typedef unsigned int u32;

#define W1H 1023   // after conv1+pool
#define W2H 1021   // after conv2
#define W3H 1019   // after conv3
#define NPIX (W3H * W3H)          // 1,038,361 < 2^20
#define IDXMASK 0xFFFFFull
#define PSTR 1024                 // padded row stride for P / H2 planes (16B-aligned rows)

#define NBINS 2048
#define HLO 0.3055f      // ln(1.5) - 0.10
#define HW_ 0.025f       // bin width
#define HINV 40.0f       // 1/HW_
#define HDELTA 0.10f     // selection margin (>= 2*|f32-f64| logit error)

// f64 weight arena offsets (in doubles)
#define W1OFF 0
#define B1OFF 270
#define P1OFF 280
#define W2OFF 290
#define B2OFF 1730
#define P2OFF 1746
#define W3OFF 1762
#define B3OFF 6370
#define P3OFF 6402
#define WAOFF 6434
#define BAOFF 6498
#define WBOFF 6500
#define BBOFF 6628
#define WDTOT 6632

// ---- prep: convert weights to f64; zero ctrl + hist ----
__global__ __launch_bounds__(256) void k_prep(
    const float* __restrict__ w1, const float* __restrict__ b1, const float* __restrict__ p1,
    const float* __restrict__ w2, const float* __restrict__ b2, const float* __restrict__ p2,
    const float* __restrict__ w3, const float* __restrict__ b3, const float* __restrict__ p3,
    const float* __restrict__ wa, const float* __restrict__ ba,
    const float* __restrict__ wb, const float* __restrict__ bb,
    double* __restrict__ wd, int* __restrict__ ctrl, u32* __restrict__ ghist)
{
    int t = threadIdx.x;
    if (t < 2) ctrl[t] = 0;
    for (int i = t; i < NBINS; i += 256) ghist[i] = 0u;
    for (int i = t; i < 270; i += 256)  wd[W1OFF + i] = (double)w1[i];
    if (t < 10) { wd[B1OFF + t] = (double)b1[t]; wd[P1OFF + t] = (double)p1[t]; }
    for (int i = t; i < 1440; i += 256) wd[W2OFF + i] = (double)w2[i];
    if (t < 16) { wd[B2OFF + t] = (double)b2[t]; wd[P2OFF + t] = (double)p2[t]; }
    for (int i = t; i < 4608; i += 256) wd[W3OFF + i] = (double)w3[i];
    if (t < 32) { wd[B3OFF + t] = (double)b3[t]; wd[P3OFF + t] = (double)p3[t]; }
    if (t < 64)  wd[WAOFF + t] = (double)wa[t];
    if (t < 2)   wd[BAOFF + t] = (double)ba[t];
    if (t < 128) wd[WBOFF + t] = (double)wb[t];
    if (t < 4)   wd[BBOFF + t] = (double)bb[t];
}

// ---------------- conv1 f32 (3->10) + bias + prelu + maxpool2 ----------------
__global__ __launch_bounds__(256) void k_conv1f(
    const float* __restrict__ x, const float* __restrict__ w1,
    const float* __restrict__ b1, const float* __restrict__ p1,
    float* __restrict__ P)
{
    __shared__ float sw[270];
    __shared__ float sb[10], sp[10];
    int t = threadIdx.y * 64 + threadIdx.x;
    for (int i = t; i < 270; i += 256) sw[i] = w1[i];
    if (t < 10) { sb[t] = b1[t]; sp[t] = p1[t]; }
    __syncthreads();
    int px = blockIdx.x * 64 + threadIdx.x;
    int py = blockIdx.y * 4 + threadIdx.y;
    if (px >= W1H || py >= W1H) return;
    int ix = px * 2, iy = py * 2;
    float acc[10][4];
    #pragma unroll
    for (int ch = 0; ch < 10; ++ch) { acc[ch][0]=0.f; acc[ch][1]=0.f; acc[ch][2]=0.f; acc[ch][3]=0.f; }
    for (int c = 0; c < 3; ++c) {
        float in[4][4];
        #pragma unroll
        for (int u = 0; u < 4; ++u) {
            const float* row = x + ((size_t)c * 2048 + (iy + u)) * 2048 + ix;
            in[u][0]=row[0]; in[u][1]=row[1]; in[u][2]=row[2]; in[u][3]=row[3];
        }
        #pragma unroll
        for (int ch = 0; ch < 10; ++ch) {
            const float* wp = sw + (ch * 3 + c) * 9;
            #pragma unroll
            for (int u = 0; u < 3; ++u)
                #pragma unroll
                for (int v = 0; v < 3; ++v) {
                    float w = wp[u * 3 + v];
                    acc[ch][0] = fmaf(in[u][v],         w, acc[ch][0]);
                    acc[ch][1] = fmaf(in[u][v + 1],     w, acc[ch][1]);
                    acc[ch][2] = fmaf(in[u + 1][v],     w, acc[ch][2]);
                    acc[ch][3] = fmaf(in[u + 1][v + 1], w, acc[ch][3]);
                }
        }
    }
    #pragma unroll
    for (int ch = 0; ch < 10; ++ch) {
        float m = fmaxf(fmaxf(acc[ch][0], acc[ch][1]), fmaxf(acc[ch][2], acc[ch][3])) + sb[ch];
        float r = m >= 0.f ? m : sp[ch] * m;
        P[((size_t)ch * W1H + py) * PSTR + px] = r;
    }
}

// ------- conv2 f32 (10->16) + bias + prelu: 8px x 4och per thread -------
__global__ __launch_bounds__(256) void k_conv2f(
    const float* __restrict__ P, const float* __restrict__ w2,
    const float* __restrict__ b2, const float* __restrict__ p2,
    float* __restrict__ H2)
{
    __shared__ __align__(16) float sw[10 * 16 * 12]; // [c][o][12] f4-padded
    __shared__ float sb[16], sp[16];
    int tx = threadIdx.x, ty = threadIdx.y;
    int t = ty * 64 + tx;
    for (int i = t; i < 1440; i += 256) {
        int o = i / 90, r = i % 90, c = r / 9, k = r % 9;
        sw[(c * 16 + o) * 12 + k] = w2[i];
    }
    if (t < 16) { sb[t] = b2[t]; sp[t] = p2[t]; }
    __syncthreads();
    int py = blockIdx.y;
    int px_base = blockIdx.x * 512 + tx * 8;
    float acc[4][8];
    #pragma unroll
    for (int j = 0; j < 4; ++j)
        #pragma unroll
        for (int p = 0; p < 8; ++p) acc[j][p] = 0.f;

    for (int c = 0; c < 10; ++c) {
        float f[3][12];
        #pragma unroll
        for (int u = 0; u < 3; ++u) {
            const float* row = P + ((size_t)c * W1H + (py + u)) * PSTR + px_base;
            float4 a = *(const float4*)(row);
            float4 b = *(const float4*)(row + 4);
            float4 d = *(const float4*)(row + 8);
            f[u][0]=a.x; f[u][1]=a.y; f[u][2]=a.z;  f[u][3]=a.w;
            f[u][4]=b.x; f[u][5]=b.y; f[u][6]=b.z;  f[u][7]=b.w;
            f[u][8]=d.x; f[u][9]=d.y; f[u][10]=d.z; f[u][11]=d.w;
        }
        #pragma unroll
        for (int j = 0; j < 4; ++j) {
            int o = ty * 4 + j;
            const float4* wv = (const float4*)(sw + (c * 16 + o) * 12);
            float4 wA = wv[0], wB = wv[1], wC = wv[2];
            float w[9] = {wA.x,wA.y,wA.z,wA.w,wB.x,wB.y,wB.z,wB.w,wC.x};
            #pragma unroll
            for (int u = 0; u < 3; ++u)
                #pragma unroll
                for (int v = 0; v < 3; ++v) {
                    float wt = w[u*3+v];
                    #pragma unroll
                    for (int p = 0; p < 8; ++p)
                        acc[j][p] = fmaf(f[u][p+v], wt, acc[j][p]);
                }
        }
    }
    #pragma unroll
    for (int j = 0; j < 4; ++j) {
        int o = ty * 4 + j;
        float bb_ = sb[o], pp_ = sp[o];
        #pragma unroll
        for (int p = 0; p < 8; ++p) {
            int px = px_base + p;
            if (px < W2H) {
                float v = acc[j][p] + bb_;
                v = v >= 0.f ? v : pp_ * v;
                H2[((size_t)o * W2H + py) * PSTR + px] = v;
            }
        }
    }
}

// ------- conv3 f32 (16->32) + prelu + cls head: 8px x 4och per thread -------
// logit plane + fused histogram; 8 waves each own 4 output channels,
// cls-head partials Σ(wa1-wa0)*prelu(v) reduced via LDS.
__global__ __launch_bounds__(512, 2) void k_conv3f(
    const float* __restrict__ H2, const float* __restrict__ w3,
    const float* __restrict__ b3, const float* __restrict__ p3,
    const float* __restrict__ wa, const float* __restrict__ ba,
    float* __restrict__ Lg, u32* __restrict__ ghist)
{
    __shared__ __align__(16) float sw[16 * 32 * 12];   // 24576 B
    __shared__ float spart[8][512];                    // 16384 B
    __shared__ u32 hist[NBINS];                        // 8192 B
    __shared__ float sb[32], sp[32], swd[32];
    __shared__ float slgb;
    int tx = threadIdx.x, ty = threadIdx.y;
    int t = ty * 64 + tx;
    for (int i = t; i < 4608; i += 512) {
        int o = i / 144, rem = i % 144, c = rem / 9, k = rem % 9;
        sw[(c * 32 + o) * 12 + k] = w3[i];
    }
    if (t < 32) { sb[t] = b3[t]; sp[t] = p3[t]; swd[t] = wa[32 + t] - wa[t]; }
    if (t == 0) slgb = ba[1] - ba[0];
    for (int i = t; i < NBINS; i += 512) hist[i] = 0u;
    __syncthreads();

    int py = blockIdx.y;
    int px_base = blockIdx.x * 512 + tx * 8;
    float acc[4][8];
    #pragma unroll
    for (int j = 0; j < 4; ++j)
        #pragma unroll
        for (int p = 0; p < 8; ++p) acc[j][p] = 0.f;

    for (int c = 0; c < 16; ++c) {
        float f[3][12];
        #pragma unroll
        for (int u = 0; u < 3; ++u) {
            const float* row = H2 + ((size_t)c * W2H + (py + u)) * PSTR + px_base;
            float4 a = *(const float4*)(row);
            float4 b = *(const float4*)(row + 4);
            float4 d = *(const float4*)(row + 8);
            f[u][0]=a.x; f[u][1]=a.y; f[u][2]=a.z;  f[u][3]=a.w;
            f[u][4]=b.x; f[u][5]=b.y; f[u][6]=b.z;  f[u][7]=b.w;
            f[u][8]=d.x; f[u][9]=d.y; f[u][10]=d.z; f[u][11]=d.w;
        }
        #pragma unroll
        for (int j = 0; j < 4; ++j) {
            int o = ty * 4 + j;
            const float4* wv = (const float4*)(sw + (c * 32 + o) * 12);
            float4 wA = wv[0], wB = wv[1], wC = wv[2];
            float w[9] = {wA.x,wA.y,wA.z,wA.w,wB.x,wB.y,wB.z,wB.w,wC.x};
            #pragma unroll
            for (int u = 0; u < 3; ++u)
                #pragma unroll
                for (int v = 0; v < 3; ++v) {
                    float wt = w[u*3+v];
                    #pragma unroll
                    for (int p = 0; p < 8; ++p)
                        acc[j][p] = fmaf(f[u][p+v], wt, acc[j][p]);
                }
        }
    }

    // per-wave partial logit per px over this wave's 4 channels
    float partv[8];
    #pragma unroll
    for (int p = 0; p < 8; ++p) partv[p] = 0.f;
    #pragma unroll
    for (int j = 0; j < 4; ++j) {
        int o = ty * 4 + j;
        float bb_ = sb[o], pp_ = sp[o], wdd = swd[o];
        #pragma unroll
        for (int p = 0; p < 8; ++p) {
            float v = acc[j][p] + bb_;
            v = v >= 0.f ? v : pp_ * v;
            partv[p] = fmaf(wdd, v, partv[p]);
        }
    }
    #pragma unroll
    for (int p = 0; p < 8; ++p) spart[ty][tx * 8 + p] = partv[p];
    __syncthreads();

    // reduce 8 partials per pixel; thread t owns px_local = t
    {
        float lg = slgb;
        #pragma unroll
        for (int g = 0; g < 8; ++g) lg += spart[g][t];
        int px = blockIdx.x * 512 + t;
        if (px < W3H) {
            Lg[(size_t)py * W3H + px] = lg;
            if (lg >= HLO) {
                int bin = (int)((lg - HLO) * HINV);
                if (bin > NBINS - 1) bin = NBINS - 1;
                atomicAdd(&hist[bin], 1u);
            }
        }
    }
    __syncthreads();
    for (int i = t; i < NBINS; i += 512) {
        u32 v = hist[i];
        if (v) atomicAdd(&ghist[i], v);
    }
}

// ---- scan: find selection threshold Tsel from histogram (rank-512 from top) ----
__global__ __launch_bounds__(256) void k_scan(
    const u32* __restrict__ ghist, int* __restrict__ ctrl)
{
    __shared__ u32 h[NBINS];
    int t = threadIdx.x;
    for (int i = t; i < NBINS; i += 256) h[i] = ghist[i];
    __syncthreads();
    if (t == 0) {
        int cum = 0, bstar = -1;
        for (int b = NBINS - 1; b >= 0; --b) {
            cum += (int)h[b];
            if (cum >= 512) { bstar = b; break; }
        }
        float T = (bstar < 0) ? HLO : (HLO + (float)bstar * HW_ - HDELTA);
        ((float*)ctrl)[2] = T;
    }
}

// ---- select: pixels with f32 logit >= Tsel ----
__global__ __launch_bounds__(256) void k_select(
    const float* __restrict__ Lg, int* __restrict__ ctrl, u32* __restrict__ selidx)
{
    float T = ((const float*)ctrl)[2];
    int stride = gridDim.x * 256;
    for (int i = blockIdx.x * 256 + threadIdx.x; i < NPIX; i += stride) {
        if (Lg[i] >= T) {
            int slot = atomicAdd(&ctrl[0], 1);
            selidx[slot] = (u32)i;
        }
    }
}

// ---- recompute: exact f64 pyramid per selected pixel; emit key + boxes ----
__global__ __launch_bounds__(64) void k_recomp(
    const float* __restrict__ x, const double* __restrict__ wd,
    const u32* __restrict__ selidx, int* __restrict__ ctrl,
    u64* __restrict__ keys, double* __restrict__ boxplane)
{
    __shared__ double xw[3][12][12];
    __shared__ double Pw[10][5][5];
    __shared__ double Hw[16][3][3];
    __shared__ double vch[32];
    int nsel = ctrl[0]; if (nsel > NPIX) nsel = NPIX;
    int t = threadIdx.x;
    for (int s = blockIdx.x; s < nsel; s += gridDim.x) {
        u32 idx = selidx[s];
        int y3 = (int)(idx / W3H), x3 = (int)(idx % W3H);
        int xr = 2 * y3, xc = 2 * x3;
        for (int i = t; i < 432; i += 64) {
            int c = i / 144, r = (i % 144) / 12, cc = i % 12;
            xw[c][r][cc] = (double)x[((size_t)c * 2048 + (xr + r)) * 2048 + (xc + cc)];
        }
        __syncthreads();
        for (int i = t; i < 250; i += 64) {
            int ch = i / 25, py = (i % 25) / 5, px = i % 5;
            int r0 = py * 2, c0 = px * 2;
            double a00=0.0, a01=0.0, a10=0.0, a11=0.0;
            for (int c = 0; c < 3; ++c) {
                const double* wp = wd + W1OFF + (ch * 3 + c) * 9;
                #pragma unroll
                for (int u = 0; u < 3; ++u)
                    #pragma unroll
                    for (int v = 0; v < 3; ++v) {
                        double w = wp[u * 3 + v];
                        a00 = fma(xw[c][r0+u][c0+v],     w, a00);
                        a01 = fma(xw[c][r0+u][c0+v+1],   w, a01);
                        a10 = fma(xw[c][r0+u+1][c0+v],   w, a10);
                        a11 = fma(xw[c][r0+u+1][c0+v+1], w, a11);
                    }
            }
            double m = fmax(fmax(a00, a01), fmax(a10, a11)) + wd[B1OFF + ch];
            Pw[ch][py][px] = m >= 0.0 ? m : wd[P1OFF + ch] * m;
        }
        __syncthreads();
        for (int i = t; i < 144; i += 64) {
            int o = i / 9, hy = (i % 9) / 3, hx = i % 3;
            double acc = 0.0;
            for (int c = 0; c < 10; ++c) {
                const double* wp = wd + W2OFF + (o * 10 + c) * 9;
                #pragma unroll
                for (int k = 0; k < 9; ++k)
                    acc = fma(Pw[c][hy + k / 3][hx + k % 3], wp[k], acc);
            }
            acc += wd[B2OFF + o];
            Hw[o][hy][hx] = acc >= 0.0 ? acc : wd[P2OFF + o] * acc;
        }
        __syncthreads();
        if (t < 32) {
            double acc = 0.0;
            for (int c = 0; c < 16; ++c) {
                const double* wp = wd + W3OFF + (t * 16 + c) * 9;
                #pragma unroll
                for (int k = 0; k < 9; ++k)
                    acc = fma(Hw[c][k / 3][k % 3], wp[k], acc);
            }
            acc += wd[B3OFF + t];
            vch[t] = acc >= 0.0 ? acc : wd[P3OFF + t] * acc;
        }
        __syncthreads();
        if (t == 0) {
            double c0 = wd[BAOFF + 0], c1 = wd[BAOFF + 1];
            for (int o = 0; o < 32; ++o) {
                c0 = fma(wd[WAOFF + o], vch[o], c0);
                c1 = fma(wd[WAOFF + 32 + o], vch[o], c1);
            }
            double mx = fmax(c0, c1);
            double e0 = exp(c0 - mx), e1 = exp(c1 - mx);
            double prob = e1 / (e0 + e1);
            if (prob >= 0.6) {
                double r0 = wd[BBOFF+0], r1 = wd[BBOFF+1], r2 = wd[BBOFF+2], r3 = wd[BBOFF+3];
                for (int o = 0; o < 32; ++o) {
                    double v = vch[o];
                    r0 = fma(wd[WBOFF + o], v, r0);
                    r1 = fma(wd[WBOFF + 32 + o], v, r1);
                    r2 = fma(wd[WBOFF + 64 + o], v, r2);
                    r3 = fma(wd[WBOFF + 96 + o], v, r3);
                }
                double fx = (double)x3, fy = (double)y3;
                double cx = (fx * 2.0 + 6.0) / 0.6;
                double cy = (fy * 2.0 + 6.0) / 0.6;
                double ww = 12.0 / 0.6, hw = ww / 2.0;
                double* bp = boxplane + (size_t)idx * 5;
                bp[0] = cx - hw + r0 * ww;
                bp[1] = cy - hw + r1 * ww;
                bp[2] = cx + hw + r2 * ww;
                bp[3] = cy + hw + r3 * ww;
                bp[4] = prob;
                u64 bits = (u64)__double_as_longlong(prob);
                u64 kh = (bits - 0x3FE0000000000000ull) >> 9;
                int slot = atomicAdd(&ctrl[1], 1);
                keys[slot] = (kh << 20) | ((u64)(~idx) & IDXMASK);
            }
        }
        __syncthreads();
    }
}

// ------- pass B: each block sorts 4 chunks of 512, keeps local top-512 (desc) -------
__global__ __launch_bounds__(512) void k_sortchunks(
    const u64* __restrict__ cand, const int* __restrict__ ctrl,
    u64* __restrict__ sorted)
{
    __shared__ u64 stop_[512];
    __shared__ u64 schunk[512];
    int tid = threadIdx.x;
    int n = ctrl[1]; if (n > NPIX) n = NPIX;
    long base0 = (long)blockIdx.x * 2048;
    stop_[tid] = 0ull;
    if (base0 < n) {
        for (int s = 0; s < 4; ++s) {
            long base = base0 + (long)s * 512;
            if (base >= n) break;
            schunk[tid] = (base + tid < n) ? cand[base + tid] : 0ull;
            for (int k = 2; k <= 512; k <<= 1)
                for (int j = k >> 1; j > 0; j >>= 1) {
                    __syncthreads();
                    int ixj = tid ^ j;
                    if (ixj > tid) {
                        u64 a = schunk[tid], b = schunk[ixj];
                        bool desc = ((tid & k) == 0);
                        if (desc ? (a < b) : (a > b)) { schunk[tid] = b; schunk[ixj] = a; }
                    }
                }
            __syncthreads();
            u64 m = stop_[tid], v = schunk[511 - tid];
            stop_[tid] = m > v ? m : v;
            for (int j = 256; j > 0; j >>= 1) {
                __syncthreads();
                int ixj = tid ^ j;
                if (ixj > tid) {
                    u64 a = stop_[tid], b = stop_[ixj];
                    if (a < b) { stop_[tid] = b; stop_[ixj] = a; }
                }
            }
            __syncthreads();
        }
    }
    sorted[(size_t)blockIdx.x * 512 + tid] = stop_[tid];
}

// ------- merge 8 consecutive sorted-512 lists -> one sorted-512 -------
__global__ __launch_bounds__(512) void k_merge8(
    const u64* __restrict__ in, u64* __restrict__ out, int nin)
{
    __shared__ u64 s[512];
    int tid = threadIdx.x;
    int base = blockIdx.x * 8;
    s[tid] = (base < nin) ? in[(size_t)base * 512 + tid] : 0ull;
    for (int c = 1; c < 8; ++c) {
        int li = base + c;
        u64 v = (li < nin) ? in[(size_t)li * 512 + (511 - tid)] : 0ull;
        __syncthreads();
        u64 m = s[tid];
        s[tid] = m > v ? m : v;
        for (int j = 256; j > 0; j >>= 1) {
            __syncthreads();
            int ixj = tid ^ j;
            if (ixj > tid) {
                u64 a = s[tid], b = s[ixj];
                if (a < b) { s[tid] = b; s[ixj] = a; }
            }
        }
        __syncthreads();
    }
    out[(size_t)blockIdx.x * 512 + tid] = s[tid];
}

// ------- final: merge 8 lists; fetch exact boxes; 2x NMS (matrix+scan) -------
__global__ __launch_bounds__(512) void k_final(
    const u64* __restrict__ lists, const double* __restrict__ boxplane,
    float* __restrict__ out)
{
    __shared__ u64 stop_[512];
    __shared__ __align__(16) char arena[53248];
    __shared__ u64 keepw[8];

    int tid = threadIdx.x;
    stop_[tid] = 0ull;
    __syncthreads();

    for (int cb = 0; cb < 8; ++cb) {
        u64 v = lists[(size_t)cb * 512 + (511 - tid)];
        u64 m = stop_[tid];
        stop_[tid] = m > v ? m : v;
        for (int j = 256; j > 0; j >>= 1) {
            __syncthreads();
            int ixj = tid ^ j;
            if (ixj > tid) {
                u64 a = stop_[tid], b = stop_[ixj];
                if (a < b) { stop_[tid] = b; stop_[ixj] = a; }
            }
        }
        __syncthreads();
    }

    u64 key = stop_[tid];
    bool valid = key != 0ull;
    double x1 = 0.0, y1 = 0.0, x2 = 0.0, y2 = 0.0, score = 0.0;
    if (valid) {
        u32 idx = (u32)(IDXMASK - (key & IDXMASK));
        const double* bp = boxplane + (size_t)idx * 5;
        x1 = bp[0]; y1 = bp[1]; x2 = bp[2]; y2 = bp[3]; score = bp[4];
    }

    u64*    mat   = (u64*)arena;
    double* bx1   = (double*)(arena + 32768);
    double* by1   = bx1 + 512;
    double* bx2   = bx1 + 1024;
    double* by2   = bx1 + 1536;
    double* sarea = bx1 + 2048;

    double area = (x2 - x1) * (y2 - y1);
    bx1[tid] = x1; by1[tid] = y1; bx2[tid] = x2; by2[tid] = y2;
    sarea[tid] = area;

    u64 bal = __ballot(valid);
    if ((tid & 63) == 0) keepw[tid >> 6] = bal;
    __syncthreads();

    for (int pass = 0; pass < 2; ++pass) {
        double thr = (pass == 0) ? 0.5 : 0.7;
        u64 accw = 0;
        for (int j = 0; j < 512; ++j) {
            double ix1 = fmax(x1, bx1[j]);
            double iy1 = fmax(y1, by1[j]);
            double ix2 = fmin(x2, bx2[j]);
            double iy2 = fmin(y2, by2[j]);
            double inter = fmax(ix2 - ix1, 0.0) * fmax(iy2 - iy1, 0.0);
            double uni = area + sarea[j] - inter + 1e-9;
            bool sup = (uni > 0.0) && (inter > thr * uni) && (j > tid);
            accw |= ((u64)sup) << (j & 63);
            if ((j & 63) == 63) { mat[tid * 8 + (j >> 6)] = accw; accw = 0; }
        }
        __syncthreads();
        if (tid < 64) {
            u64 kw = (tid < 8) ? keepw[tid] : 0ull;
            for (int i = 0; i < 512; ++i) {
                u64 row = mat[i * 8 + (tid & 7)];
                u64 cur = __shfl(kw, i >> 6);
                if ((cur >> (i & 63)) & 1) kw &= ~row;
            }
            if (tid < 8) keepw[tid] = kw;
        }
        __syncthreads();
    }

    double kf = ((keepw[tid >> 6] >> (tid & 63)) & 1) ? 1.0 : 0.0;
    out[tid * 5 + 0] = (float)(x1 * kf);
    out[tid * 5 + 1] = (float)(y1 * kf);
    out[tid * 5 + 2] = (float)(x2 * kf);
    out[tid * 5 + 3] = (float)(y2 * kf);
    out[tid * 5 + 4] = (float)(score * kf);
}

extern "C" void kernel_launch(void* const* d_in, const int* in_sizes, int n_in,
                              void* d_out, int out_size, void* d_ws, size_t ws_size,
                              hipStream_t stream)
{
    const float* x  = (const float*)d_in[0];
    const float* w1 = (const float*)d_in[1];
    const float* b1 = (const float*)d_in[2];
    const float* p1 = (const float*)d_in[3];
    const float* w2 = (const float*)d_in[4];
    const float* b2 = (const float*)d_in[5];
    const float* p2 = (const float*)d_in[6];
    const float* w3 = (const float*)d_in[7];
    const float* b3 = (const float*)d_in[8];
    const float* p3 = (const float*)d_in[9];
    const float* wa = (const float*)d_in[10];
    const float* ba = (const float*)d_in[11];
    const float* wb = (const float*)d_in[12];
    const float* bb = (const float*)d_in[13];
    float* out = (float*)d_out;

    char* ws = (char*)d_ws;
    float*  Pf    = (float*) (ws);                       // 10*1023*1024*4 = 41,902,080
    float*  H2f   = (float*) (ws + 41902080);            // 16*1021*1024*4 = 66,912,256
    float*  Lg    = (float*) (ws + 108814336);           // NPIX*4 -> pad 4,153,600
    u32*    ghist = (u32*)   (ws + 112967936);           // 8192
    int*    ctrl  = (int*)   (ws + 112976128);           // 256: [0]=selcnt [1]=emit [2]=Tsel(f32)
    u32*    selidx= (u32*)   (ws + 112976384);           // NPIX*4 -> 4,153,600
    u64*    keys  = (u64*)   (ws + 117129984);           // NPIX*8 -> 8,307,200
    u64*    sorted= (u64*)   (ws + 125437184);           // 508*512*8 = 2,080,768
    u64*    l1out = (u64*)   (ws + 127517952);           // 64*512*8 = 262,144
    u64*    l2out = (u64*)   (ws + 127780096);           // 8*512*8 = 32,768
    double* boxpl = (double*)(ws + 127812864);           // NPIX*5*8 -> 41,534,720
    double* wd    = (double*)(ws + 169347584);           // WDTOT*8 = 53,056

    k_prep<<<1, 256, 0, stream>>>(w1, b1, p1, w2, b2, p2, w3, b3, p3, wa, ba, wb, bb, wd, ctrl, ghist);
    k_conv1f<<<dim3(16, 256), dim3(64, 4), 0, stream>>>(x, w1, b1, p1, Pf);
    k_conv2f<<<dim3(2, W2H), dim3(64, 4), 0, stream>>>(Pf, w2, b2, p2, H2f);
    k_conv3f<<<dim3(2, W3H), dim3(64, 8), 0, stream>>>(H2f, w3, b3, p3, wa, ba, Lg, ghist);
    k_scan<<<1, 256, 0, stream>>>(ghist, ctrl);
    k_select<<<1024, 256, 0, stream>>>(Lg, ctrl, selidx);
    k_recomp<<<2048, 64, 0, stream>>>(x, wd, selidx, ctrl, keys, boxpl);
    k_sortchunks<<<508, 512, 0, stream>>>(keys, ctrl, sorted);
    k_merge8<<<64, 512, 0, stream>>>(sorted, l1out, 508);
    k_merge8<<<8, 512, 0, stream>>>(l1out, l2out, 64);
    k_final<<<1, 512, 0, stream>>>(l2out, boxpl, out);
}

// Round 8
// 601.049 us; speedup vs baseline: 9.1145x; 1.2562x over previous
//
#include <hip/hip_runtime.h>

typedef unsigned long long u64;
typedef unsigned int u32;

#define W1H 1023   // after conv1+pool
#define W2H 1021   // after conv2
#define W3H 1019   // after conv3
#define NPIX (W3H * W3H)          // 1,038,361 < 2^20
#define IDXMASK 0xFFFFFull
#define PSTR 1024                 // padded row stride for P / H2 planes (16B-aligned rows)

#define NBINS 2048
#define HLO 0.3055f      // ln(1.5) - 0.10
#define HW_ 0.025f       // bin width
#define HINV 40.0f       // 1/HW_
#define HDELTA 0.10f     // selection margin (>= 2*|f32-f64| logit error)

// f64 weight arena offsets (in doubles)
#define W1OFF 0
#define B1OFF 270
#define P1OFF 280
#define W2OFF 290
#define B2OFF 1730
#define P2OFF 1746
#define W3OFF 1762
#define B3OFF 6370
#define P3OFF 6402
#define WAOFF 6434
#define BAOFF 6498
#define WBOFF 6500
#define BBOFF 6628
#define WDTOT 6632

// ---- prep: convert weights to f64; zero ctrl + hist ----
__global__ __launch_bounds__(256) void k_prep(
    const float* __restrict__ w1, const float* __restrict__ b1, const float* __restrict__ p1,
    const float* __restrict__ w2, const float* __restrict__ b2, const float* __restrict__ p2,
    const float* __restrict__ w3, const float* __restrict__ b3, const float* __restrict__ p3,
    const float* __restrict__ wa, const float* __restrict__ ba,
    const float* __restrict__ wb, const float* __restrict__ bb,
    double* __restrict__ wd, int* __restrict__ ctrl, u32* __restrict__ ghist)
{
    int t = threadIdx.x;
    if (t < 2) ctrl[t] = 0;
    for (int i = t; i < NBINS; i += 256) ghist[i] = 0u;
    for (int i = t; i < 270; i += 256)  wd[W1OFF + i] = (double)w1[i];
    if (t < 10) { wd[B1OFF + t] = (double)b1[t]; wd[P1OFF + t] = (double)p1[t]; }
    for (int i = t; i < 1440; i += 256) wd[W2OFF + i] = (double)w2[i];
    if (t < 16) { wd[B2OFF + t] = (double)b2[t]; wd[P2OFF + t] = (double)p2[t]; }
    for (int i = t; i < 4608; i += 256) wd[W3OFF + i] = (double)w3[i];
    if (t < 32) { wd[B3OFF + t] = (double)b3[t]; wd[P3OFF + t] = (double)p3[t]; }
    if (t < 64)  wd[WAOFF + t] = (double)wa[t];
    if (t < 2)   wd[BAOFF + t] = (double)ba[t];
    if (t < 128) wd[WBOFF + t] = (double)wb[t];
    if (t < 4)   wd[BBOFF + t] = (double)bb[t];
}

// ---------------- conv1 f32 (3->10) + bias + prelu + maxpool2 ----------------
__global__ __launch_bounds__(256) void k_conv1f(
    const float* __restrict__ x, const float* __restrict__ w1,
    const float* __restrict__ b1, const float* __restrict__ p1,
    float* __restrict__ P)
{
    __shared__ float sw[270];
    __shared__ float sb[10], sp[10];
    int t = threadIdx.y * 64 + threadIdx.x;
    for (int i = t; i < 270; i += 256) sw[i] = w1[i];
    if (t < 10) { sb[t] = b1[t]; sp[t] = p1[t]; }
    __syncthreads();
    int px = blockIdx.x * 64 + threadIdx.x;
    int py = blockIdx.y * 4 + threadIdx.y;
    if (px >= W1H || py >= W1H) return;
    int ix = px * 2, iy = py * 2;
    float acc[10][4];
    #pragma unroll
    for (int ch = 0; ch < 10; ++ch) { acc[ch][0]=0.f; acc[ch][1]=0.f; acc[ch][2]=0.f; acc[ch][3]=0.f; }
    for (int c = 0; c < 3; ++c) {
        float in[4][4];
        #pragma unroll
        for (int u = 0; u < 4; ++u) {
            const float* row = x + ((size_t)c * 2048 + (iy + u)) * 2048 + ix;
            in[u][0]=row[0]; in[u][1]=row[1]; in[u][2]=row[2]; in[u][3]=row[3];
        }
        #pragma unroll
        for (int ch = 0; ch < 10; ++ch) {
            const float* wp = sw + (ch * 3 + c) * 9;
            #pragma unroll
            for (int u = 0; u < 3; ++u)
                #pragma unroll
                for (int v = 0; v < 3; ++v) {
                    float w = wp[u * 3 + v];
                    acc[ch][0] = fmaf(in[u][v],         w, acc[ch][0]);
                    acc[ch][1] = fmaf(in[u][v + 1],     w, acc[ch][1]);
                    acc[ch][2] = fmaf(in[u + 1][v],     w, acc[ch][2]);
                    acc[ch][3] = fmaf(in[u + 1][v + 1], w, acc[ch][3]);
                }
        }
    }
    #pragma unroll
    for (int ch = 0; ch < 10; ++ch) {
        float m = fmaxf(fmaxf(acc[ch][0], acc[ch][1]), fmaxf(acc[ch][2], acc[ch][3])) + sb[ch];
        float r = m >= 0.f ? m : sp[ch] * m;
        P[((size_t)ch * W1H + py) * PSTR + px] = r;
    }
}

// ------- conv2 f32 (10->16) + bias + prelu: 8px x 4och per thread -------
__global__ __launch_bounds__(256) void k_conv2f(
    const float* __restrict__ P, const float* __restrict__ w2,
    const float* __restrict__ b2, const float* __restrict__ p2,
    float* __restrict__ H2)
{
    __shared__ __align__(16) float sw[10 * 16 * 12]; // [c][o][12] f4-padded
    __shared__ float sb[16], sp[16];
    int tx = threadIdx.x, ty = threadIdx.y;
    int t = ty * 64 + tx;
    for (int i = t; i < 1440; i += 256) {
        int o = i / 90, r = i % 90, c = r / 9, k = r % 9;
        sw[(c * 16 + o) * 12 + k] = w2[i];
    }
    if (t < 16) { sb[t] = b2[t]; sp[t] = p2[t]; }
    __syncthreads();
    int py = blockIdx.y;
    int px_base = blockIdx.x * 512 + tx * 8;
    float acc[4][8];
    #pragma unroll
    for (int j = 0; j < 4; ++j)
        #pragma unroll
        for (int p = 0; p < 8; ++p) acc[j][p] = 0.f;

    for (int c = 0; c < 10; ++c) {
        float f[3][12];
        #pragma unroll
        for (int u = 0; u < 3; ++u) {
            const float* row = P + ((size_t)c * W1H + (py + u)) * PSTR + px_base;
            float4 a = *(const float4*)(row);
            float4 b = *(const float4*)(row + 4);
            float4 d = *(const float4*)(row + 8);
            f[u][0]=a.x; f[u][1]=a.y; f[u][2]=a.z;  f[u][3]=a.w;
            f[u][4]=b.x; f[u][5]=b.y; f[u][6]=b.z;  f[u][7]=b.w;
            f[u][8]=d.x; f[u][9]=d.y; f[u][10]=d.z; f[u][11]=d.w;
        }
        #pragma unroll
        for (int j = 0; j < 4; ++j) {
            int o = ty * 4 + j;
            const float4* wv = (const float4*)(sw + (c * 16 + o) * 12);
            float4 wA = wv[0], wB = wv[1], wC = wv[2];
            float w[9] = {wA.x,wA.y,wA.z,wA.w,wB.x,wB.y,wB.z,wB.w,wC.x};
            #pragma unroll
            for (int u = 0; u < 3; ++u)
                #pragma unroll
                for (int v = 0; v < 3; ++v) {
                    float wt = w[u*3+v];
                    #pragma unroll
                    for (int p = 0; p < 8; ++p)
                        acc[j][p] = fmaf(f[u][p+v], wt, acc[j][p]);
                }
        }
    }
    #pragma unroll
    for (int j = 0; j < 4; ++j) {
        int o = ty * 4 + j;
        float bb_ = sb[o], pp_ = sp[o];
        #pragma unroll
        for (int p = 0; p < 8; ++p) {
            int px = px_base + p;
            if (px < W2H) {
                float v = acc[j][p] + bb_;
                v = v >= 0.f ? v : pp_ * v;
                H2[((size_t)o * W2H + py) * PSTR + px] = v;
            }
        }
    }
}

// ------- conv3 f32 (16->32) + prelu + cls head: 8px x 4och per thread -------
__global__ __launch_bounds__(512, 2) void k_conv3f(
    const float* __restrict__ H2, const float* __restrict__ w3,
    const float* __restrict__ b3, const float* __restrict__ p3,
    const float* __restrict__ wa, const float* __restrict__ ba,
    float* __restrict__ Lg, u32* __restrict__ ghist)
{
    __shared__ __align__(16) float sw[16 * 32 * 12];   // 24576 B
    __shared__ float spart[8][512];                    // 16384 B
    __shared__ u32 hist[NBINS];                        // 8192 B
    __shared__ float sb[32], sp[32], swd[32];
    __shared__ float slgb;
    int tx = threadIdx.x, ty = threadIdx.y;
    int t = ty * 64 + tx;
    for (int i = t; i < 4608; i += 512) {
        int o = i / 144, rem = i % 144, c = rem / 9, k = rem % 9;
        sw[(c * 32 + o) * 12 + k] = w3[i];
    }
    if (t < 32) { sb[t] = b3[t]; sp[t] = p3[t]; swd[t] = wa[32 + t] - wa[t]; }
    if (t == 0) slgb = ba[1] - ba[0];
    for (int i = t; i < NBINS; i += 512) hist[i] = 0u;
    __syncthreads();

    int py = blockIdx.y;
    int px_base = blockIdx.x * 512 + tx * 8;
    float acc[4][8];
    #pragma unroll
    for (int j = 0; j < 4; ++j)
        #pragma unroll
        for (int p = 0; p < 8; ++p) acc[j][p] = 0.f;

    for (int c = 0; c < 16; ++c) {
        float f[3][12];
        #pragma unroll
        for (int u = 0; u < 3; ++u) {
            const float* row = H2 + ((size_t)c * W2H + (py + u)) * PSTR + px_base;
            float4 a = *(const float4*)(row);
            float4 b = *(const float4*)(row + 4);
            float4 d = *(const float4*)(row + 8);
            f[u][0]=a.x; f[u][1]=a.y; f[u][2]=a.z;  f[u][3]=a.w;
            f[u][4]=b.x; f[u][5]=b.y; f[u][6]=b.z;  f[u][7]=b.w;
            f[u][8]=d.x; f[u][9]=d.y; f[u][10]=d.z; f[u][11]=d.w;
        }
        #pragma unroll
        for (int j = 0; j < 4; ++j) {
            int o = ty * 4 + j;
            const float4* wv = (const float4*)(sw + (c * 32 + o) * 12);
            float4 wA = wv[0], wB = wv[1], wC = wv[2];
            float w[9] = {wA.x,wA.y,wA.z,wA.w,wB.x,wB.y,wB.z,wB.w,wC.x};
            #pragma unroll
            for (int u = 0; u < 3; ++u)
                #pragma unroll
                for (int v = 0; v < 3; ++v) {
                    float wt = w[u*3+v];
                    #pragma unroll
                    for (int p = 0; p < 8; ++p)
                        acc[j][p] = fmaf(f[u][p+v], wt, acc[j][p]);
                }
        }
    }

    float partv[8];
    #pragma unroll
    for (int p = 0; p < 8; ++p) partv[p] = 0.f;
    #pragma unroll
    for (int j = 0; j < 4; ++j) {
        int o = ty * 4 + j;
        float bb_ = sb[o], pp_ = sp[o], wdd = swd[o];
        #pragma unroll
        for (int p = 0; p < 8; ++p) {
            float v = acc[j][p] + bb_;
            v = v >= 0.f ? v : pp_ * v;
            partv[p] = fmaf(wdd, v, partv[p]);
        }
    }
    #pragma unroll
    for (int p = 0; p < 8; ++p) spart[ty][tx * 8 + p] = partv[p];
    __syncthreads();

    {
        float lg = slgb;
        #pragma unroll
        for (int g = 0; g < 8; ++g) lg += spart[g][t];
        int px = blockIdx.x * 512 + t;
        if (px < W3H) {
            Lg[(size_t)py * W3H + px] = lg;
            if (lg >= HLO) {
                int bin = (int)((lg - HLO) * HINV);
                if (bin > NBINS - 1) bin = NBINS - 1;
                atomicAdd(&hist[bin], 1u);
            }
        }
    }
    __syncthreads();
    for (int i = t; i < NBINS; i += 512) {
        u32 v = hist[i];
        if (v) atomicAdd(&ghist[i], v);
    }
}

// ---- scan (parallel): find Tsel = floor of rank-512-from-top bin, minus margin ----
__global__ __launch_bounds__(256) void k_scan(
    const u32* __restrict__ ghist, int* __restrict__ ctrl)
{
    __shared__ u32 h[NBINS];
    __shared__ u32 tsum[256];
    __shared__ int best;
    int t = threadIdx.x;
    for (int i = t; i < NBINS; i += 256) h[i] = ghist[i];
    if (t == 0) best = -1;
    __syncthreads();
    u32 s = 0;
    #pragma unroll
    for (int k = 0; k < 8; ++k) s += h[t * 8 + k];
    tsum[t] = s;
    __syncthreads();
    // suffix-scan: tsum[t] = sum over t'>=t
    for (int off = 1; off < 256; off <<= 1) {
        u32 add = (t + off < 256) ? tsum[t + off] : 0u;
        __syncthreads();
        tsum[t] += add;
        __syncthreads();
    }
    u32 cum = (t < 255) ? tsum[t + 1] : 0u;
    int cand = -1;
    for (int k = 7; k >= 0; --k) {
        cum += h[t * 8 + k];
        if (cand < 0 && cum >= 512) cand = t * 8 + k;
    }
    if (cand >= 0) atomicMax(&best, cand);
    __syncthreads();
    if (t == 0) {
        float T = (best < 0) ? HLO : (HLO + (float)best * HW_ - HDELTA);
        ((float*)ctrl)[2] = T;
    }
}

// ---- select: pixels with f32 logit >= Tsel ----
__global__ __launch_bounds__(256) void k_select(
    const float* __restrict__ Lg, int* __restrict__ ctrl, u32* __restrict__ selidx)
{
    float T = ((const float*)ctrl)[2];
    int stride = gridDim.x * 256;
    for (int i = blockIdx.x * 256 + threadIdx.x; i < NPIX; i += stride) {
        if (Lg[i] >= T) {
            int slot = atomicAdd(&ctrl[0], 1);
            selidx[slot] = (u32)i;
        }
    }
}

// ---- recompute: exact f64 pyramid per selected pixel; emit key + boxes ----
__global__ __launch_bounds__(64) void k_recomp(
    const float* __restrict__ x, const double* __restrict__ wd,
    const u32* __restrict__ selidx, int* __restrict__ ctrl,
    u64* __restrict__ keys, double* __restrict__ boxplane)
{
    __shared__ double xw[3][12][12];
    __shared__ double Pw[10][5][5];
    __shared__ double Hw[16][3][3];
    __shared__ double vch[32];
    int nsel = ctrl[0]; if (nsel > NPIX) nsel = NPIX;
    int t = threadIdx.x;
    for (int s = blockIdx.x; s < nsel; s += gridDim.x) {
        u32 idx = selidx[s];
        int y3 = (int)(idx / W3H), x3 = (int)(idx % W3H);
        int xr = 2 * y3, xc = 2 * x3;
        for (int i = t; i < 432; i += 64) {
            int c = i / 144, r = (i % 144) / 12, cc = i % 12;
            xw[c][r][cc] = (double)x[((size_t)c * 2048 + (xr + r)) * 2048 + (xc + cc)];
        }
        __syncthreads();
        for (int i = t; i < 250; i += 64) {
            int ch = i / 25, py = (i % 25) / 5, px = i % 5;
            int r0 = py * 2, c0 = px * 2;
            double a00=0.0, a01=0.0, a10=0.0, a11=0.0;
            for (int c = 0; c < 3; ++c) {
                const double* wp = wd + W1OFF + (ch * 3 + c) * 9;
                #pragma unroll
                for (int u = 0; u < 3; ++u)
                    #pragma unroll
                    for (int v = 0; v < 3; ++v) {
                        double w = wp[u * 3 + v];
                        a00 = fma(xw[c][r0+u][c0+v],     w, a00);
                        a01 = fma(xw[c][r0+u][c0+v+1],   w, a01);
                        a10 = fma(xw[c][r0+u+1][c0+v],   w, a10);
                        a11 = fma(xw[c][r0+u+1][c0+v+1], w, a11);
                    }
            }
            double m = fmax(fmax(a00, a01), fmax(a10, a11)) + wd[B1OFF + ch];
            Pw[ch][py][px] = m >= 0.0 ? m : wd[P1OFF + ch] * m;
        }
        __syncthreads();
        for (int i = t; i < 144; i += 64) {
            int o = i / 9, hy = (i % 9) / 3, hx = i % 3;
            double acc = 0.0;
            for (int c = 0; c < 10; ++c) {
                const double* wp = wd + W2OFF + (o * 10 + c) * 9;
                #pragma unroll
                for (int k = 0; k < 9; ++k)
                    acc = fma(Pw[c][hy + k / 3][hx + k % 3], wp[k], acc);
            }
            acc += wd[B2OFF + o];
            Hw[o][hy][hx] = acc >= 0.0 ? acc : wd[P2OFF + o] * acc;
        }
        __syncthreads();
        if (t < 32) {
            double acc = 0.0;
            for (int c = 0; c < 16; ++c) {
                const double* wp = wd + W3OFF + (t * 16 + c) * 9;
                #pragma unroll
                for (int k = 0; k < 9; ++k)
                    acc = fma(Hw[c][k / 3][k % 3], wp[k], acc);
            }
            acc += wd[B3OFF + t];
            vch[t] = acc >= 0.0 ? acc : wd[P3OFF + t] * acc;
        }
        __syncthreads();
        if (t == 0) {
            double c0 = wd[BAOFF + 0], c1 = wd[BAOFF + 1];
            for (int o = 0; o < 32; ++o) {
                c0 = fma(wd[WAOFF + o], vch[o], c0);
                c1 = fma(wd[WAOFF + 32 + o], vch[o], c1);
            }
            double mx = fmax(c0, c1);
            double e0 = exp(c0 - mx), e1 = exp(c1 - mx);
            double prob = e1 / (e0 + e1);
            if (prob >= 0.6) {
                double r0 = wd[BBOFF+0], r1 = wd[BBOFF+1], r2 = wd[BBOFF+2], r3 = wd[BBOFF+3];
                for (int o = 0; o < 32; ++o) {
                    double v = vch[o];
                    r0 = fma(wd[WBOFF + o], v, r0);
                    r1 = fma(wd[WBOFF + 32 + o], v, r1);
                    r2 = fma(wd[WBOFF + 64 + o], v, r2);
                    r3 = fma(wd[WBOFF + 96 + o], v, r3);
                }
                double fx = (double)x3, fy = (double)y3;
                double cx = (fx * 2.0 + 6.0) / 0.6;
                double cy = (fy * 2.0 + 6.0) / 0.6;
                double ww = 12.0 / 0.6, hw = ww / 2.0;
                double* bp = boxplane + (size_t)idx * 5;
                bp[0] = cx - hw + r0 * ww;
                bp[1] = cy - hw + r1 * ww;
                bp[2] = cx + hw + r2 * ww;
                bp[3] = cy + hw + r3 * ww;
                bp[4] = prob;
                u64 bits = (u64)__double_as_longlong(prob);
                u64 kh = (bits - 0x3FE0000000000000ull) >> 9;
                int slot = atomicAdd(&ctrl[1], 1);
                keys[slot] = (kh << 20) | ((u64)(~idx) & IDXMASK);
            }
        }
        __syncthreads();
    }
}

// ------- pass B: each block sorts 4 chunks of 512, keeps local top-512 (desc) -------
__global__ __launch_bounds__(512) void k_sortchunks(
    const u64* __restrict__ cand, const int* __restrict__ ctrl,
    u64* __restrict__ sorted)
{
    __shared__ u64 stop_[512];
    __shared__ u64 schunk[512];
    int tid = threadIdx.x;
    int n = ctrl[1]; if (n > NPIX) n = NPIX;
    long base0 = (long)blockIdx.x * 2048;
    stop_[tid] = 0ull;
    if (base0 < n) {
        for (int s = 0; s < 4; ++s) {
            long base = base0 + (long)s * 512;
            if (base >= n) break;
            schunk[tid] = (base + tid < n) ? cand[base + tid] : 0ull;
            for (int k = 2; k <= 512; k <<= 1)
                for (int j = k >> 1; j > 0; j >>= 1) {
                    __syncthreads();
                    int ixj = tid ^ j;
                    if (ixj > tid) {
                        u64 a = schunk[tid], b = schunk[ixj];
                        bool desc = ((tid & k) == 0);
                        if (desc ? (a < b) : (a > b)) { schunk[tid] = b; schunk[ixj] = a; }
                    }
                }
            __syncthreads();
            u64 m = stop_[tid], v = schunk[511 - tid];
            stop_[tid] = m > v ? m : v;
            for (int j = 256; j > 0; j >>= 1) {
                __syncthreads();
                int ixj = tid ^ j;
                if (ixj > tid) {
                    u64 a = stop_[tid], b = stop_[ixj];
                    if (a < b) { stop_[tid] = b; stop_[ixj] = a; }
                }
            }
            __syncthreads();
        }
    }
    sorted[(size_t)blockIdx.x * 512 + tid] = stop_[tid];
}

// ------- merge 8 consecutive sorted-512 lists -> one sorted-512 -------
__global__ __launch_bounds__(512) void k_merge8(
    const u64* __restrict__ in, u64* __restrict__ out, int nin)
{
    __shared__ u64 s[512];
    int tid = threadIdx.x;
    int base = blockIdx.x * 8;
    s[tid] = (base < nin) ? in[(size_t)base * 512 + tid] : 0ull;
    for (int c = 1; c < 8; ++c) {
        int li = base + c;
        u64 v = (li < nin) ? in[(size_t)li * 512 + (511 - tid)] : 0ull;
        __syncthreads();
        u64 m = s[tid];
        s[tid] = m > v ? m : v;
        for (int j = 256; j > 0; j >>= 1) {
            __syncthreads();
            int ixj = tid ^ j;
            if (ixj > tid) {
                u64 a = s[tid], b = s[ixj];
                if (a < b) { s[tid] = b; s[ixj] = a; }
            }
        }
        __syncthreads();
    }
    out[(size_t)blockIdx.x * 512 + tid] = s[tid];
}

// ------- boxmat: parallel build of both suppression bit-matrices + box SoA -------
// grid (8, 2): blockIdx.x = 64-row group, blockIdx.y = pass (thr .5 / .7)
__global__ __launch_bounds__(512) void k_boxmat(
    const u64* __restrict__ lists, const double* __restrict__ boxplane,
    u64* __restrict__ mats, double* __restrict__ bxs, u64* __restrict__ validw)
{
    __shared__ double sx1[512], sy1[512], sx2[512], sy2[512], sar[512];
    int tid = threadIdx.x;
    u64 key = lists[tid];
    bool valid = key != 0ull;
    double x1 = 0.0, y1 = 0.0, x2 = 0.0, y2 = 0.0, score = 0.0;
    if (valid) {
        u32 idx = (u32)(IDXMASK - (key & IDXMASK));
        const double* bp = boxplane + (size_t)idx * 5;
        x1 = bp[0]; y1 = bp[1]; x2 = bp[2]; y2 = bp[3]; score = bp[4];
    }
    double area = (x2 - x1) * (y2 - y1);
    sx1[tid] = x1; sy1[tid] = y1; sx2[tid] = x2; sy2[tid] = y2; sar[tid] = area;
    if (blockIdx.x == 0 && blockIdx.y == 0) {
        bxs[tid] = x1; bxs[512 + tid] = y1; bxs[1024 + tid] = x2;
        bxs[1536 + tid] = y2; bxs[2048 + tid] = score;
        u64 bal = __ballot(valid);
        if ((tid & 63) == 0) validw[tid >> 6] = bal;
    }
    __syncthreads();
    double thr = (blockIdx.y == 0) ? 0.5 : 0.7;
    int wv = tid >> 6;     // wave index -> column word
    int rowbase = blockIdx.x * 64;
    for (int r = 0; r < 64; ++r) {
        int i = rowbase + r;
        double ix1 = fmax(sx1[i], x1);
        double iy1 = fmax(sy1[i], y1);
        double ix2 = fmin(sx2[i], x2);
        double iy2 = fmin(sy2[i], y2);
        double inter = fmax(ix2 - ix1, 0.0) * fmax(iy2 - iy1, 0.0);
        double uni = sar[i] + area - inter + 1e-9;
        bool sup = (uni > 0.0) && (inter > thr * uni) && (tid > i);
        u64 w = __ballot(sup);
        if ((tid & 63) == 0)
            mats[((size_t)blockIdx.y * 512 + i) * 8 + wv] = w;
    }
}

// ------- nmsfin: two serial greedy scans over precomputed matrices; output -------
__global__ __launch_bounds__(512) void k_nmsfin(
    const u64* __restrict__ mats, const double* __restrict__ bxs,
    const u64* __restrict__ validw, float* __restrict__ out)
{
    __shared__ u64 keepw[8];
    int tid = threadIdx.x;
    if (tid < 8) keepw[tid] = validw[tid];
    __syncthreads();
    for (int pass = 0; pass < 2; ++pass) {
        if (tid < 64) {
            const u64* mat = mats + (size_t)pass * 512 * 8;
            u64 kw = (tid < 8) ? keepw[tid] : 0ull;
            for (int i = 0; i < 512; ++i) {
                u64 row = mat[i * 8 + (tid & 7)];
                u64 cur = __shfl(kw, i >> 6);
                if ((cur >> (i & 63)) & 1) kw &= ~row;
            }
            if (tid < 8) keepw[tid] = kw;
        }
        __syncthreads();
    }
    double kf = ((keepw[tid >> 6] >> (tid & 63)) & 1) ? 1.0 : 0.0;
    out[tid * 5 + 0] = (float)(bxs[tid] * kf);
    out[tid * 5 + 1] = (float)(bxs[512 + tid] * kf);
    out[tid * 5 + 2] = (float)(bxs[1024 + tid] * kf);
    out[tid * 5 + 3] = (float)(bxs[1536 + tid] * kf);
    out[tid * 5 + 4] = (float)(bxs[2048 + tid] * kf);
}

extern "C" void kernel_launch(void* const* d_in, const int* in_sizes, int n_in,
                              void* d_out, int out_size, void* d_ws, size_t ws_size,
                              hipStream_t stream)
{
    const float* x  = (const float*)d_in[0];
    const float* w1 = (const float*)d_in[1];
    const float* b1 = (const float*)d_in[2];
    const float* p1 = (const float*)d_in[3];
    const float* w2 = (const float*)d_in[4];
    const float* b2 = (const float*)d_in[5];
    const float* p2 = (const float*)d_in[6];
    const float* w3 = (const float*)d_in[7];
    const float* b3 = (const float*)d_in[8];
    const float* p3 = (const float*)d_in[9];
    const float* wa = (const float*)d_in[10];
    const float* ba = (const float*)d_in[11];
    const float* wb = (const float*)d_in[12];
    const float* bb = (const float*)d_in[13];
    float* out = (float*)d_out;

    char* ws = (char*)d_ws;
    float*  Pf    = (float*) (ws);                       // 10*1023*1024*4 = 41,902,080
    float*  H2f   = (float*) (ws + 41902080);            // 16*1021*1024*4 = 66,912,256
    float*  Lg    = (float*) (ws + 108814336);           // NPIX*4 -> 4,153,600
    u32*    ghist = (u32*)   (ws + 112967936);           // 8192
    int*    ctrl  = (int*)   (ws + 112976128);           // 256: [0]=selcnt [1]=emit [2]=Tsel(f32)
    u32*    selidx= (u32*)   (ws + 112976384);           // NPIX*4 -> 4,153,600
    u64*    keys  = (u64*)   (ws + 117129984);           // NPIX*8 -> 8,307,200
    u64*    sorted= (u64*)   (ws + 125437184);           // 508*512*8 = 2,080,768
    u64*    l1out = (u64*)   (ws + 127517952);           // 64*512*8 = 262,144
    u64*    l2out = (u64*)   (ws + 127780096);           // 8*512*8 = 32,768
    double* boxpl = (double*)(ws + 127812864);           // NPIX*5*8 -> 41,534,720
    double* wd    = (double*)(ws + 169347584);           // WDTOT*8 = 53,056
    // carved inside 'sorted' region (free after merge level 1):
    u64*    l3out = (u64*)   (ws + 125437184);           // 512*8 = 4,096
    u64*    mats  = (u64*)   (ws + 125441280);           // 2*512*8*8 = 65,536
    double* bxs   = (double*)(ws + 125506816);           // 5*512*8 = 20,480
    u64*    vwords= (u64*)   (ws + 125527296);           // 64

    k_prep<<<1, 256, 0, stream>>>(w1, b1, p1, w2, b2, p2, w3, b3, p3, wa, ba, wb, bb, wd, ctrl, ghist);
    k_conv1f<<<dim3(16, 256), dim3(64, 4), 0, stream>>>(x, w1, b1, p1, Pf);
    k_conv2f<<<dim3(2, W2H), dim3(64, 4), 0, stream>>>(Pf, w2, b2, p2, H2f);
    k_conv3f<<<dim3(2, W3H), dim3(64, 8), 0, stream>>>(H2f, w3, b3, p3, wa, ba, Lg, ghist);
    k_scan<<<1, 256, 0, stream>>>(ghist, ctrl);
    k_select<<<1024, 256, 0, stream>>>(Lg, ctrl, selidx);
    k_recomp<<<2048, 64, 0, stream>>>(x, wd, selidx, ctrl, keys, boxpl);
    k_sortchunks<<<508, 512, 0, stream>>>(keys, ctrl, sorted);
    k_merge8<<<64, 512, 0, stream>>>(sorted, l1out, 508);
    k_merge8<<<8, 512, 0, stream>>>(l1out, l2out, 64);
    k_merge8<<<1, 512, 0, stream>>>(l2out, l3out, 8);
    k_boxmat<<<dim3(8, 2), 512, 0, stream>>>(l3out, boxpl, mats, bxs, vwords);
    k_nmsfin<<<1, 512, 0, stream>>>(mats, bxs, vwords, out);
}

// Round 9
// 590.624 us; speedup vs baseline: 9.2754x; 1.0177x over previous
//
#include <hip/hip_runtime.h>

typedef unsigned long long u64;
typedef unsigned int u32;

#define W1H 1023   // after conv1+pool
#define W2H 1021   // after conv2
#define W3H 1019   // after conv3
#define NPIX (W3H * W3H)          // 1,038,361 < 2^20
#define IDXMASK 0xFFFFFull
#define PSTR 1024                 // padded row stride for P / H2 planes

#define NBINS 2048
#define HLO 0.3055f      // ln(1.5) - 0.10
#define HW_ 0.025f       // bin width
#define HINV 40.0f       // 1/HW_
#define HDELTA 0.10f     // selection margin (>= 2*|f32-f64| logit error)

// f64 weight arena offsets (in doubles)
#define W1OFF 0
#define B1OFF 270
#define P1OFF 280
#define W2OFF 290
#define B2OFF 1730
#define P2OFF 1746
#define W3OFF 1762
#define B3OFF 6370
#define P3OFF 6402
#define WAOFF 6434
#define BAOFF 6498
#define WBOFF 6500
#define BBOFF 6628
#define WDTOT 6632

// ---- prep: convert weights to f64; zero ctrl + hist ----
__global__ __launch_bounds__(256) void k_prep(
    const float* __restrict__ w1, const float* __restrict__ b1, const float* __restrict__ p1,
    const float* __restrict__ w2, const float* __restrict__ b2, const float* __restrict__ p2,
    const float* __restrict__ w3, const float* __restrict__ b3, const float* __restrict__ p3,
    const float* __restrict__ wa, const float* __restrict__ ba,
    const float* __restrict__ wb, const float* __restrict__ bb,
    double* __restrict__ wd, int* __restrict__ ctrl, u32* __restrict__ ghist)
{
    int t = threadIdx.x;
    if (t < 2) ctrl[t] = 0;
    for (int i = t; i < NBINS; i += 256) ghist[i] = 0u;
    for (int i = t; i < 270; i += 256)  wd[W1OFF + i] = (double)w1[i];
    if (t < 10) { wd[B1OFF + t] = (double)b1[t]; wd[P1OFF + t] = (double)p1[t]; }
    for (int i = t; i < 1440; i += 256) wd[W2OFF + i] = (double)w2[i];
    if (t < 16) { wd[B2OFF + t] = (double)b2[t]; wd[P2OFF + t] = (double)p2[t]; }
    for (int i = t; i < 4608; i += 256) wd[W3OFF + i] = (double)w3[i];
    if (t < 32) { wd[B3OFF + t] = (double)b3[t]; wd[P3OFF + t] = (double)p3[t]; }
    if (t < 64)  wd[WAOFF + t] = (double)wa[t];
    if (t < 2)   wd[BAOFF + t] = (double)ba[t];
    if (t < 128) wd[WBOFF + t] = (double)wb[t];
    if (t < 4)   wd[BBOFF + t] = (double)bb[t];
}

// ---------------- conv1 f32 (3->10) + bias + prelu + maxpool2, LDS-staged x ----------------
__global__ __launch_bounds__(256) void k_conv1f(
    const float* __restrict__ x, const float* __restrict__ w1,
    const float* __restrict__ b1, const float* __restrict__ p1,
    float* __restrict__ P)
{
    __shared__ float sw[270];
    __shared__ float sb[10], sp[10];
    __shared__ float xs[3][10][132];
    int tx = threadIdx.x, ty = threadIdx.y;
    int t = ty * 64 + tx;
    for (int i = t; i < 270; i += 256) sw[i] = w1[i];
    if (t < 10) { sb[t] = b1[t]; sp[t] = p1[t]; }
    int bx = blockIdx.x, by = blockIdx.y;
    // stage x tile: 3ch x 10 rows x 33 float4 (cols 128*bx .. +131, clamped)
    const float4* x4 = (const float4*)x;
    for (int i = t; i < 990; i += 256) {
        int c = i / 330, rem = i % 330, r = rem / 33, k = rem % 33;
        int row = 8 * by + r; if (row > 2047) row = 2047;
        int col4 = bx * 32 + k; if (col4 > 511) col4 = 511;
        float4 v = x4[((size_t)c * 2048 + row) * 512 + col4];
        xs[c][r][k * 4 + 0] = v.x; xs[c][r][k * 4 + 1] = v.y;
        xs[c][r][k * 4 + 2] = v.z; xs[c][r][k * 4 + 3] = v.w;
    }
    __syncthreads();
    int px = bx * 64 + tx;
    int py = by * 4 + ty;
    if (px >= W1H || py >= W1H) return;
    float acc[10][4];
    #pragma unroll
    for (int ch = 0; ch < 10; ++ch) { acc[ch][0]=0.f; acc[ch][1]=0.f; acc[ch][2]=0.f; acc[ch][3]=0.f; }
    for (int c = 0; c < 3; ++c) {
        float in[4][4];
        #pragma unroll
        for (int u = 0; u < 4; ++u) {
            in[u][0] = xs[c][2*ty+u][2*tx+0];
            in[u][1] = xs[c][2*ty+u][2*tx+1];
            in[u][2] = xs[c][2*ty+u][2*tx+2];
            in[u][3] = xs[c][2*ty+u][2*tx+3];
        }
        #pragma unroll
        for (int ch = 0; ch < 10; ++ch) {
            const float* wp = sw + (ch * 3 + c) * 9;
            #pragma unroll
            for (int u = 0; u < 3; ++u)
                #pragma unroll
                for (int v = 0; v < 3; ++v) {
                    float w = wp[u * 3 + v];
                    acc[ch][0] = fmaf(in[u][v],         w, acc[ch][0]);
                    acc[ch][1] = fmaf(in[u][v + 1],     w, acc[ch][1]);
                    acc[ch][2] = fmaf(in[u + 1][v],     w, acc[ch][2]);
                    acc[ch][3] = fmaf(in[u + 1][v + 1], w, acc[ch][3]);
                }
        }
    }
    #pragma unroll
    for (int ch = 0; ch < 10; ++ch) {
        float m = fmaxf(fmaxf(acc[ch][0], acc[ch][1]), fmaxf(acc[ch][2], acc[ch][3])) + sb[ch];
        float r = m >= 0.f ? m : sp[ch] * m;
        P[((size_t)ch * W1H + py) * PSTR + px] = r;
    }
}

// ------- conv2 f32 (10->16) + bias + prelu: 8px x 8och per thread -------
// block (64,4): ty&1 = och group (x8), ty>>1 = px half (x512); block covers 1024px x 16och
__global__ __launch_bounds__(256) void k_conv2f(
    const float* __restrict__ P, const float* __restrict__ w2,
    const float* __restrict__ b2, const float* __restrict__ p2,
    float* __restrict__ H2)
{
    __shared__ __align__(16) float sw[10 * 16 * 12]; // [c][o][12] f4-padded
    __shared__ float sb[16], sp[16];
    int tx = threadIdx.x, ty = threadIdx.y;
    int t = ty * 64 + tx;
    for (int i = t; i < 1440; i += 256) {
        int o = i / 90, r = i % 90, c = r / 9, k = r % 9;
        sw[(c * 16 + o) * 12 + k] = w2[i];
    }
    if (t < 16) { sb[t] = b2[t]; sp[t] = p2[t]; }
    __syncthreads();
    int py = blockIdx.y;
    int och0 = (ty & 1) * 8;
    int px_base = (ty >> 1) * 512 + tx * 8;
    float acc[8][8];
    #pragma unroll
    for (int j = 0; j < 8; ++j)
        #pragma unroll
        for (int p = 0; p < 8; ++p) acc[j][p] = 0.f;

    for (int c = 0; c < 10; ++c) {
        float f[3][12];
        #pragma unroll
        for (int u = 0; u < 3; ++u) {
            const float* row = P + ((size_t)c * W1H + (py + u)) * PSTR + px_base;
            float4 a = *(const float4*)(row);
            float4 b = *(const float4*)(row + 4);
            float4 d = *(const float4*)(row + 8);
            f[u][0]=a.x; f[u][1]=a.y; f[u][2]=a.z;  f[u][3]=a.w;
            f[u][4]=b.x; f[u][5]=b.y; f[u][6]=b.z;  f[u][7]=b.w;
            f[u][8]=d.x; f[u][9]=d.y; f[u][10]=d.z; f[u][11]=d.w;
        }
        #pragma unroll
        for (int j = 0; j < 8; ++j) {
            int o = och0 + j;
            const float4* wv = (const float4*)(sw + (c * 16 + o) * 12);
            float4 wA = wv[0], wB = wv[1], wC = wv[2];
            float w[9] = {wA.x,wA.y,wA.z,wA.w,wB.x,wB.y,wB.z,wB.w,wC.x};
            #pragma unroll
            for (int u = 0; u < 3; ++u)
                #pragma unroll
                for (int v = 0; v < 3; ++v) {
                    float wt = w[u*3+v];
                    #pragma unroll
                    for (int p = 0; p < 8; ++p)
                        acc[j][p] = fmaf(f[u][p+v], wt, acc[j][p]);
                }
        }
    }
    #pragma unroll
    for (int j = 0; j < 8; ++j) {
        int o = och0 + j;
        float bb_ = sb[o], pp_ = sp[o];
        #pragma unroll
        for (int p = 0; p < 8; ++p) {
            int px = px_base + p;
            if (px < W2H) {
                float v = acc[j][p] + bb_;
                v = v >= 0.f ? v : pp_ * v;
                H2[((size_t)o * W2H + py) * PSTR + px] = v;
            }
        }
    }
}

// ------- conv3 f32 (16->32) + prelu + cls head: 8px x 8och per thread -------
// block (64,8): ty&3 = och group (x8), ty>>2 = px half (x512); block covers 1024px x 32och
__global__ __launch_bounds__(512, 2) void k_conv3f(
    const float* __restrict__ H2, const float* __restrict__ w3,
    const float* __restrict__ b3, const float* __restrict__ p3,
    const float* __restrict__ wa, const float* __restrict__ ba,
    float* __restrict__ Lg, u32* __restrict__ ghist)
{
    __shared__ __align__(16) float sw[16 * 32 * 12];   // 24576 B
    __shared__ float spart[4][1024];                   // 16384 B
    __shared__ u32 hist[NBINS];                        // 8192 B
    __shared__ float sb[32], sp[32], swd[32];
    __shared__ float slgb;
    int tx = threadIdx.x, ty = threadIdx.y;
    int t = ty * 64 + tx;
    for (int i = t; i < 4608; i += 512) {
        int o = i / 144, rem = i % 144, c = rem / 9, k = rem % 9;
        sw[(c * 32 + o) * 12 + k] = w3[i];
    }
    if (t < 32) { sb[t] = b3[t]; sp[t] = p3[t]; swd[t] = wa[32 + t] - wa[t]; }
    if (t == 0) slgb = ba[1] - ba[0];
    for (int i = t; i < NBINS; i += 512) hist[i] = 0u;
    __syncthreads();

    int py = blockIdx.y;
    int och0 = (ty & 3) * 8;
    int px_base = (ty >> 2) * 512 + tx * 8;
    float acc[8][8];
    #pragma unroll
    for (int j = 0; j < 8; ++j)
        #pragma unroll
        for (int p = 0; p < 8; ++p) acc[j][p] = 0.f;

    for (int c = 0; c < 16; ++c) {
        float f[3][12];
        #pragma unroll
        for (int u = 0; u < 3; ++u) {
            const float* row = H2 + ((size_t)c * W2H + (py + u)) * PSTR + px_base;
            float4 a = *(const float4*)(row);
            float4 b = *(const float4*)(row + 4);
            float4 d = *(const float4*)(row + 8);
            f[u][0]=a.x; f[u][1]=a.y; f[u][2]=a.z;  f[u][3]=a.w;
            f[u][4]=b.x; f[u][5]=b.y; f[u][6]=b.z;  f[u][7]=b.w;
            f[u][8]=d.x; f[u][9]=d.y; f[u][10]=d.z; f[u][11]=d.w;
        }
        #pragma unroll
        for (int j = 0; j < 8; ++j) {
            int o = och0 + j;
            const float4* wv = (const float4*)(sw + (c * 32 + o) * 12);
            float4 wA = wv[0], wB = wv[1], wC = wv[2];
            float w[9] = {wA.x,wA.y,wA.z,wA.w,wB.x,wB.y,wB.z,wB.w,wC.x};
            #pragma unroll
            for (int u = 0; u < 3; ++u)
                #pragma unroll
                for (int v = 0; v < 3; ++v) {
                    float wt = w[u*3+v];
                    #pragma unroll
                    for (int p = 0; p < 8; ++p)
                        acc[j][p] = fmaf(f[u][p+v], wt, acc[j][p]);
                }
        }
    }

    // per-thread partial logit over its 8 channels
    float partv[8];
    #pragma unroll
    for (int p = 0; p < 8; ++p) partv[p] = 0.f;
    #pragma unroll
    for (int j = 0; j < 8; ++j) {
        int o = och0 + j;
        float bb_ = sb[o], pp_ = sp[o], wdd = swd[o];
        #pragma unroll
        for (int p = 0; p < 8; ++p) {
            float v = acc[j][p] + bb_;
            v = v >= 0.f ? v : pp_ * v;
            partv[p] = fmaf(wdd, v, partv[p]);
        }
    }
    #pragma unroll
    for (int p = 0; p < 8; ++p) spart[ty & 3][px_base + p] = partv[p];
    __syncthreads();

    // reduce 4 partials per pixel; thread t owns px t and t+512
    #pragma unroll
    for (int rep = 0; rep < 2; ++rep) {
        int pl = t + rep * 512;
        float lg = slgb;
        #pragma unroll
        for (int g = 0; g < 4; ++g) lg += spart[g][pl];
        if (pl < W3H) {
            Lg[(size_t)py * W3H + pl] = lg;
            if (lg >= HLO) {
                int bin = (int)((lg - HLO) * HINV);
                if (bin > NBINS - 1) bin = NBINS - 1;
                atomicAdd(&hist[bin], 1u);
            }
        }
    }
    __syncthreads();
    for (int i = t; i < NBINS; i += 512) {
        u32 v = hist[i];
        if (v) atomicAdd(&ghist[i], v);
    }
}

// ---- select (with fused threshold scan): pixels with f32 logit >= Tsel ----
__global__ __launch_bounds__(256) void k_select(
    const float* __restrict__ Lg, const u32* __restrict__ ghist,
    int* __restrict__ ctrl, u32* __restrict__ selidx)
{
    __shared__ u32 h[NBINS];
    __shared__ u32 tsum[256];
    __shared__ int best;
    __shared__ float sT;
    int t = threadIdx.x;
    for (int i = t; i < NBINS; i += 256) h[i] = ghist[i];
    if (t == 0) best = -1;
    __syncthreads();
    u32 s = 0;
    #pragma unroll
    for (int k = 0; k < 8; ++k) s += h[t * 8 + k];
    tsum[t] = s;
    __syncthreads();
    for (int off = 1; off < 256; off <<= 1) {
        u32 add = (t + off < 256) ? tsum[t + off] : 0u;
        __syncthreads();
        tsum[t] += add;
        __syncthreads();
    }
    u32 cum = (t < 255) ? tsum[t + 1] : 0u;
    int cand = -1;
    for (int k = 7; k >= 0; --k) {
        cum += h[t * 8 + k];
        if (cand < 0 && cum >= 512) cand = t * 8 + k;
    }
    if (cand >= 0) atomicMax(&best, cand);
    __syncthreads();
    if (t == 0) sT = (best < 0) ? HLO : (HLO + (float)best * HW_ - HDELTA);
    __syncthreads();
    float T = sT;
    int stride = gridDim.x * 256;
    for (int i = blockIdx.x * 256 + t; i < NPIX; i += stride) {
        if (Lg[i] >= T) {
            int slot = atomicAdd(&ctrl[0], 1);
            selidx[slot] = (u32)i;
        }
    }
}

// ---- recompute: exact f64 pyramid per selected pixel; emit key + boxes ----
__global__ __launch_bounds__(64) void k_recomp(
    const float* __restrict__ x, const double* __restrict__ wd,
    const u32* __restrict__ selidx, int* __restrict__ ctrl,
    u64* __restrict__ keys, double* __restrict__ boxplane)
{
    __shared__ double xw[3][12][12];
    __shared__ double Pw[10][5][5];
    __shared__ double Hw[16][3][3];
    __shared__ double vch[32];
    int nsel = ctrl[0]; if (nsel > NPIX) nsel = NPIX;
    int t = threadIdx.x;
    for (int s = blockIdx.x; s < nsel; s += gridDim.x) {
        u32 idx = selidx[s];
        int y3 = (int)(idx / W3H), x3 = (int)(idx % W3H);
        int xr = 2 * y3, xc = 2 * x3;
        for (int i = t; i < 432; i += 64) {
            int c = i / 144, r = (i % 144) / 12, cc = i % 12;
            xw[c][r][cc] = (double)x[((size_t)c * 2048 + (xr + r)) * 2048 + (xc + cc)];
        }
        __syncthreads();
        for (int i = t; i < 250; i += 64) {
            int ch = i / 25, py = (i % 25) / 5, px = i % 5;
            int r0 = py * 2, c0 = px * 2;
            double a00=0.0, a01=0.0, a10=0.0, a11=0.0;
            for (int c = 0; c < 3; ++c) {
                const double* wp = wd + W1OFF + (ch * 3 + c) * 9;
                #pragma unroll
                for (int u = 0; u < 3; ++u)
                    #pragma unroll
                    for (int v = 0; v < 3; ++v) {
                        double w = wp[u * 3 + v];
                        a00 = fma(xw[c][r0+u][c0+v],     w, a00);
                        a01 = fma(xw[c][r0+u][c0+v+1],   w, a01);
                        a10 = fma(xw[c][r0+u+1][c0+v],   w, a10);
                        a11 = fma(xw[c][r0+u+1][c0+v+1], w, a11);
                    }
            }
            double m = fmax(fmax(a00, a01), fmax(a10, a11)) + wd[B1OFF + ch];
            Pw[ch][py][px] = m >= 0.0 ? m : wd[P1OFF + ch] * m;
        }
        __syncthreads();
        for (int i = t; i < 144; i += 64) {
            int o = i / 9, hy = (i % 9) / 3, hx = i % 3;
            double acc = 0.0;
            for (int c = 0; c < 10; ++c) {
                const double* wp = wd + W2OFF + (o * 10 + c) * 9;
                #pragma unroll
                for (int k = 0; k < 9; ++k)
                    acc = fma(Pw[c][hy + k / 3][hx + k % 3], wp[k], acc);
            }
            acc += wd[B2OFF + o];
            Hw[o][hy][hx] = acc >= 0.0 ? acc : wd[P2OFF + o] * acc;
        }
        __syncthreads();
        if (t < 32) {
            double acc = 0.0;
            for (int c = 0; c < 16; ++c) {
                const double* wp = wd + W3OFF + (t * 16 + c) * 9;
                #pragma unroll
                for (int k = 0; k < 9; ++k)
                    acc = fma(Hw[c][k / 3][k % 3], wp[k], acc);
            }
            acc += wd[B3OFF + t];
            vch[t] = acc >= 0.0 ? acc : wd[P3OFF + t] * acc;
        }
        __syncthreads();
        if (t == 0) {
            double c0 = wd[BAOFF + 0], c1 = wd[BAOFF + 1];
            for (int o = 0; o < 32; ++o) {
                c0 = fma(wd[WAOFF + o], vch[o], c0);
                c1 = fma(wd[WAOFF + 32 + o], vch[o], c1);
            }
            double mx = fmax(c0, c1);
            double e0 = exp(c0 - mx), e1 = exp(c1 - mx);
            double prob = e1 / (e0 + e1);
            if (prob >= 0.6) {
                double r0 = wd[BBOFF+0], r1 = wd[BBOFF+1], r2 = wd[BBOFF+2], r3 = wd[BBOFF+3];
                for (int o = 0; o < 32; ++o) {
                    double v = vch[o];
                    r0 = fma(wd[WBOFF + o], v, r0);
                    r1 = fma(wd[WBOFF + 32 + o], v, r1);
                    r2 = fma(wd[WBOFF + 64 + o], v, r2);
                    r3 = fma(wd[WBOFF + 96 + o], v, r3);
                }
                double fx = (double)x3, fy = (double)y3;
                double cx = (fx * 2.0 + 6.0) / 0.6;
                double cy = (fy * 2.0 + 6.0) / 0.6;
                double ww = 12.0 / 0.6, hw = ww / 2.0;
                double* bp = boxplane + (size_t)idx * 5;
                bp[0] = cx - hw + r0 * ww;
                bp[1] = cy - hw + r1 * ww;
                bp[2] = cx + hw + r2 * ww;
                bp[3] = cy + hw + r3 * ww;
                bp[4] = prob;
                u64 bits = (u64)__double_as_longlong(prob);
                u64 kh = (bits - 0x3FE0000000000000ull) >> 9;
                int slot = atomicAdd(&ctrl[1], 1);
                keys[slot] = (kh << 20) | ((u64)(~idx) & IDXMASK);
            }
        }
        __syncthreads();
    }
}

// ------- pass B: each block sorts 4 chunks of 512, keeps local top-512 (desc) -------
__global__ __launch_bounds__(512) void k_sortchunks(
    const u64* __restrict__ cand, const int* __restrict__ ctrl,
    u64* __restrict__ sorted)
{
    __shared__ u64 stop_[512];
    __shared__ u64 schunk[512];
    int tid = threadIdx.x;
    int n = ctrl[1]; if (n > NPIX) n = NPIX;
    long base0 = (long)blockIdx.x * 2048;
    stop_[tid] = 0ull;
    if (base0 < n) {
        for (int s = 0; s < 4; ++s) {
            long base = base0 + (long)s * 512;
            if (base >= n) break;
            schunk[tid] = (base + tid < n) ? cand[base + tid] : 0ull;
            for (int k = 2; k <= 512; k <<= 1)
                for (int j = k >> 1; j > 0; j >>= 1) {
                    __syncthreads();
                    int ixj = tid ^ j;
                    if (ixj > tid) {
                        u64 a = schunk[tid], b = schunk[ixj];
                        bool desc = ((tid & k) == 0);
                        if (desc ? (a < b) : (a > b)) { schunk[tid] = b; schunk[ixj] = a; }
                    }
                }
            __syncthreads();
            u64 m = stop_[tid], v = schunk[511 - tid];
            stop_[tid] = m > v ? m : v;
            for (int j = 256; j > 0; j >>= 1) {
                __syncthreads();
                int ixj = tid ^ j;
                if (ixj > tid) {
                    u64 a = stop_[tid], b = stop_[ixj];
                    if (a < b) { stop_[tid] = b; stop_[ixj] = a; }
                }
            }
            __syncthreads();
        }
    }
    sorted[(size_t)blockIdx.x * 512 + tid] = stop_[tid];
}

// ------- merge 8 consecutive sorted-512 lists -> one sorted-512 -------
__global__ __launch_bounds__(512) void k_merge8(
    const u64* __restrict__ in, u64* __restrict__ out, int nin)
{
    __shared__ u64 s[512];
    int tid = threadIdx.x;
    int base = blockIdx.x * 8;
    s[tid] = (base < nin) ? in[(size_t)base * 512 + tid] : 0ull;
    for (int c = 1; c < 8; ++c) {
        int li = base + c;
        u64 v = (li < nin) ? in[(size_t)li * 512 + (511 - tid)] : 0ull;
        __syncthreads();
        u64 m = s[tid];
        s[tid] = m > v ? m : v;
        for (int j = 256; j > 0; j >>= 1) {
            __syncthreads();
            int ixj = tid ^ j;
            if (ixj > tid) {
                u64 a = s[tid], b = s[ixj];
                if (a < b) { s[tid] = b; s[ixj] = a; }
            }
        }
        __syncthreads();
    }
    out[(size_t)blockIdx.x * 512 + tid] = s[tid];
}

// ------- boxmat: parallel build of both suppression bit-matrices + box SoA -------
__global__ __launch_bounds__(512) void k_boxmat(
    const u64* __restrict__ lists, const double* __restrict__ boxplane,
    u64* __restrict__ mats, double* __restrict__ bxs, u64* __restrict__ validw)
{
    __shared__ double sx1[512], sy1[512], sx2[512], sy2[512], sar[512];
    int tid = threadIdx.x;
    u64 key = lists[tid];
    bool valid = key != 0ull;
    double x1 = 0.0, y1 = 0.0, x2 = 0.0, y2 = 0.0, score = 0.0;
    if (valid) {
        u32 idx = (u32)(IDXMASK - (key & IDXMASK));
        const double* bp = boxplane + (size_t)idx * 5;
        x1 = bp[0]; y1 = bp[1]; x2 = bp[2]; y2 = bp[3]; score = bp[4];
    }
    double area = (x2 - x1) * (y2 - y1);
    sx1[tid] = x1; sy1[tid] = y1; sx2[tid] = x2; sy2[tid] = y2; sar[tid] = area;
    if (blockIdx.x == 0 && blockIdx.y == 0) {
        bxs[tid] = x1; bxs[512 + tid] = y1; bxs[1024 + tid] = x2;
        bxs[1536 + tid] = y2; bxs[2048 + tid] = score;
        u64 bal = __ballot(valid);
        if ((tid & 63) == 0) validw[tid >> 6] = bal;
    }
    __syncthreads();
    double thr = (blockIdx.y == 0) ? 0.5 : 0.7;
    int wv = tid >> 6;
    int rowbase = blockIdx.x * 64;
    for (int r = 0; r < 64; ++r) {
        int i = rowbase + r;
        double ix1 = fmax(sx1[i], x1);
        double iy1 = fmax(sy1[i], y1);
        double ix2 = fmin(sx2[i], x2);
        double iy2 = fmin(sy2[i], y2);
        double inter = fmax(ix2 - ix1, 0.0) * fmax(iy2 - iy1, 0.0);
        double uni = sar[i] + area - inter + 1e-9;
        bool sup = (uni > 0.0) && (inter > thr * uni) && (tid > i);
        u64 w = __ballot(sup);
        if ((tid & 63) == 0)
            mats[((size_t)blockIdx.y * 512 + i) * 8 + wv] = w;
    }
}

// ------- nmsfin: two serial greedy scans over precomputed matrices; output -------
__global__ __launch_bounds__(512) void k_nmsfin(
    const u64* __restrict__ mats, const double* __restrict__ bxs,
    const u64* __restrict__ validw, float* __restrict__ out)
{
    __shared__ u64 keepw[8];
    int tid = threadIdx.x;
    if (tid < 8) keepw[tid] = validw[tid];
    __syncthreads();
    for (int pass = 0; pass < 2; ++pass) {
        if (tid < 64) {
            const u64* mat = mats + (size_t)pass * 512 * 8;
            u64 kw = (tid < 8) ? keepw[tid] : 0ull;
            for (int i = 0; i < 512; ++i) {
                u64 row = mat[i * 8 + (tid & 7)];
                u64 cur = __shfl(kw, i >> 6);
                if ((cur >> (i & 63)) & 1) kw &= ~row;
            }
            if (tid < 8) keepw[tid] = kw;
        }
        __syncthreads();
    }
    double kf = ((keepw[tid >> 6] >> (tid & 63)) & 1) ? 1.0 : 0.0;
    out[tid * 5 + 0] = (float)(bxs[tid] * kf);
    out[tid * 5 + 1] = (float)(bxs[512 + tid] * kf);
    out[tid * 5 + 2] = (float)(bxs[1024 + tid] * kf);
    out[tid * 5 + 3] = (float)(bxs[1536 + tid] * kf);
    out[tid * 5 + 4] = (float)(bxs[2048 + tid] * kf);
}

extern "C" void kernel_launch(void* const* d_in, const int* in_sizes, int n_in,
                              void* d_out, int out_size, void* d_ws, size_t ws_size,
                              hipStream_t stream)
{
    const float* x  = (const float*)d_in[0];
    const float* w1 = (const float*)d_in[1];
    const float* b1 = (const float*)d_in[2];
    const float* p1 = (const float*)d_in[3];
    const float* w2 = (const float*)d_in[4];
    const float* b2 = (const float*)d_in[5];
    const float* p2 = (const float*)d_in[6];
    const float* w3 = (const float*)d_in[7];
    const float* b3 = (const float*)d_in[8];
    const float* p3 = (const float*)d_in[9];
    const float* wa = (const float*)d_in[10];
    const float* ba = (const float*)d_in[11];
    const float* wb = (const float*)d_in[12];
    const float* bb = (const float*)d_in[13];
    float* out = (float*)d_out;

    char* ws = (char*)d_ws;
    float*  Pf    = (float*) (ws);                       // 10*1023*1024*4 = 41,902,080
    float*  H2f   = (float*) (ws + 41902080);            // 16*1021*1024*4 = 66,912,256
    float*  Lg    = (float*) (ws + 108814336);           // NPIX*4 -> 4,153,600
    u32*    ghist = (u32*)   (ws + 112967936);           // 8192
    int*    ctrl  = (int*)   (ws + 112976128);           // 256: [0]=selcnt [1]=emit
    u32*    selidx= (u32*)   (ws + 112976384);           // NPIX*4 -> 4,153,600
    u64*    keys  = (u64*)   (ws + 117129984);           // NPIX*8 -> 8,307,200
    u64*    sorted= (u64*)   (ws + 125437184);           // 508*512*8 = 2,080,768
    u64*    l1out = (u64*)   (ws + 127517952);           // 64*512*8 = 262,144
    u64*    l2out = (u64*)   (ws + 127780096);           // 8*512*8 = 32,768
    double* boxpl = (double*)(ws + 127812864);           // NPIX*5*8 -> 41,534,720
    double* wd    = (double*)(ws + 169347584);           // WDTOT*8 = 53,056
    u64*    l3out = (u64*)   (ws + 125437184);           // aliases sorted (free by then)
    u64*    mats  = (u64*)   (ws + 125441280);           // 2*512*8*8 = 65,536
    double* bxs   = (double*)(ws + 125506816);           // 5*512*8 = 20,480
    u64*    vwords= (u64*)   (ws + 125527296);           // 64

    k_prep<<<1, 256, 0, stream>>>(w1, b1, p1, w2, b2, p2, w3, b3, p3, wa, ba, wb, bb, wd, ctrl, ghist);
    k_conv1f<<<dim3(16, 256), dim3(64, 4), 0, stream>>>(x, w1, b1, p1, Pf);
    k_conv2f<<<dim3(1, W2H), dim3(64, 4), 0, stream>>>(Pf, w2, b2, p2, H2f);
    k_conv3f<<<dim3(1, W3H), dim3(64, 8), 0, stream>>>(H2f, w3, b3, p3, wa, ba, Lg, ghist);
    k_select<<<1024, 256, 0, stream>>>(Lg, ghist, ctrl, selidx);
    k_recomp<<<2048, 64, 0, stream>>>(x, wd, selidx, ctrl, keys, boxpl);
    k_sortchunks<<<508, 512, 0, stream>>>(keys, ctrl, sorted);
    k_merge8<<<64, 512, 0, stream>>>(sorted, l1out, 508);
    k_merge8<<<8, 512, 0, stream>>>(l1out, l2out, 64);
    k_merge8<<<1, 512, 0, stream>>>(l2out, l3out, 8);
    k_boxmat<<<dim3(8, 2), 512, 0, stream>>>(l3out, boxpl, mats, bxs, vwords);
    k_nmsfin<<<1, 512, 0, stream>>>(mats, bxs, vwords, out);
}